// Round 5
// baseline (674.020 us; speedup 1.0000x reference)
//
#include <hip/hip_runtime.h>

#define LEAKY(v) ((v) >= 0.0f ? (v) : 0.2f * (v))

typedef __attribute__((ext_vector_type(8))) short bf16x8;
typedef __attribute__((ext_vector_type(4))) float f32x4;

__device__ __forceinline__ unsigned short f2bf(float f) {
    unsigned int u = __float_as_uint(f);
    unsigned int r = u + 0x7FFFu + ((u >> 16) & 1u);
    return (unsigned short)(r >> 16);
}
__device__ __forceinline__ float bf2f(unsigned short u) {
    return __uint_as_float(((unsigned int)u) << 16);
}
__device__ __forceinline__ unsigned int pk2(float a, float b) {
    return (unsigned int)f2bf(a) | ((unsigned int)f2bf(b) << 16);
}
__device__ __forceinline__ float lo16(unsigned int u) { return __uint_as_float(u << 16); }
__device__ __forceinline__ float hi16(unsigned int u) { return __uint_as_float(u & 0xFFFF0000u); }

// ---------------- CSR build ----------------

__global__ __launch_bounds__(256) void count_deg(const int* ei, int* deg, int E, int Etot) {
    int i = blockIdx.x * 256 + threadIdx.x;
    if (i >= Etot) return;
    int d = (i < E) ? ei[E + i] : (i - E);
    atomicAdd(&deg[d], 1);
}

__global__ __launch_bounds__(512) void scan_block(const int* deg, int* excl, int* bsum, int n) {
    __shared__ int s[512];
    int t = threadIdx.x;
    int i = blockIdx.x * 512 + t;
    int v = (i < n) ? deg[i] : 0;
    s[t] = v;
    __syncthreads();
    for (int d = 1; d < 512; d <<= 1) {
        int x = 0;
        if (t >= d) x = s[t - d];
        __syncthreads();
        if (t >= d) s[t] += x;
        __syncthreads();
    }
    if (i < n) excl[i] = s[t] - v;
    if (t == 511) bsum[blockIdx.x] = s[511];
}

__global__ __launch_bounds__(512) void scan_sums(const int* bsum, int* boff, int nb) {
    __shared__ int s[512];
    int t = threadIdx.x;
    int v = (t < nb) ? bsum[t] : 0;
    s[t] = v;
    __syncthreads();
    for (int d = 1; d < 512; d <<= 1) {
        int x = 0;
        if (t >= d) x = s[t - d];
        __syncthreads();
        if (t >= d) s[t] += x;
        __syncthreads();
    }
    boff[t] = s[t] - v;
}

__global__ __launch_bounds__(256) void finalize_off(int* csr, int* cursor, const int* boff, int n, int etot) {
    int i = blockIdx.x * 256 + threadIdx.x;
    if (i < n) {
        int v = csr[i] + boff[i >> 9];
        csr[i] = v;
        cursor[i] = v;
    }
    if (i == 0) csr[n] = etot;
}

__global__ __launch_bounds__(256) void scatter_src(const int* ei, int* cursor, int* srcs, int E, int Etot) {
    int i = blockIdx.x * 256 + threadIdx.x;
    if (i >= Etot) return;
    int s, d;
    if (i < E) { s = ei[i]; d = ei[E + i]; }
    else       { s = i - E; d = s; }
    int pos = atomicAdd(&cursor[d], 1);
    srcs[pos] = s;
}

// ---------------- weight packing ----------------

// W1 (f32 [2][128][256]) -> wt1 (bf16 [2][256 c][128 k], transposed, swizzle baked)
__global__ __launch_bounds__(256) void wpack1(const float* __restrict__ W1, unsigned short* __restrict__ wt1) {
    int id = blockIdx.x * 256 + threadIdx.x;      // conv*4096 + c*16 + q
    if (id >= 8192) return;
    int conv = id >> 12, rem = id & 4095;
    int c = rem >> 4, q = rem & 15;
    const float* src = W1 + (size_t)conv * 32768 + (size_t)(q * 8) * 256 + c;
    float w[8];
#pragma unroll
    for (int j = 0; j < 8; ++j) w[j] = src[j * 256];
    uint4 v;
    v.x = pk2(w[0], w[1]); v.y = pk2(w[2], w[3]);
    v.z = pk2(w[4], w[5]); v.w = pk2(w[6], w[7]);
    *(uint4*)(wt1 + (size_t)conv * 32768 + c * 128 + ((q ^ (c & 7)) << 3)) = v;
}

// W2 (f32 [512][16]) -> wt2 (bf16 B-fragment image [16 steps][64 lanes][8])
__global__ __launch_bounds__(256) void wpack2(const float* __restrict__ W2, unsigned short* __restrict__ wt2) {
    int id = blockIdx.x * 256 + threadIdx.x;      // s*64 + l
    if (id >= 1024) return;
    int s = id >> 6, l = id & 63;
    const float* src = W2 + (size_t)(s * 32 + (l >> 4) * 8) * 16 + (l & 15);
    float w[8];
#pragma unroll
    for (int j = 0; j < 8; ++j) w[j] = src[j * 16];
    uint4 v;
    v.x = pk2(w[0], w[1]); v.y = pk2(w[2], w[3]);
    v.z = pk2(w[4], w[5]); v.w = pk2(w[6], w[7]);
    *(uint4*)(wt2 + (size_t)id * 8) = v;
}

// ---------------- GEMM1 MFMA (fused f32->bf16 staging + fused alpha) ----------------
// block: 64 rows x 256 cols; 4 waves, wave w = head w
// hp layout: [conv][n][c(64)][head(4)] bf16  (512 B per node per conv)

__global__ __launch_bounds__(256) void gemm1_mfma(const float* __restrict__ x_list,
                                                  const unsigned short* __restrict__ wt1,
                                                  const float* __restrict__ asw, const float* __restrict__ adw,
                                                  unsigned short* __restrict__ hp,
                                                  float* __restrict__ as1, float* __restrict__ ad1, int N) {
    __shared__ unsigned short As[64 * 128];    // 16 KB swizzled
    __shared__ unsigned short Ws[256 * 128];   // 64 KB swizzled
    int conv = blockIdx.y;
    int t = threadIdx.x;
    int w = t >> 6, l = t & 63;

    const float* xg = x_list + (size_t)conv * N * 128;
#pragma unroll
    for (int p = 0; p < 4; ++p) {
        int id = p * 256 + t;
        int row = id >> 4, q = id & 15;
        int grow = blockIdx.x * 64 + row;
        uint4 v = make_uint4(0, 0, 0, 0);
        if (grow < N) {
            const float* src = xg + (size_t)grow * 128 + q * 8;
            float4 a = *(const float4*)src;
            float4 b = *(const float4*)(src + 4);
            v.x = pk2(a.x, a.y); v.y = pk2(a.z, a.w);
            v.z = pk2(b.x, b.y); v.w = pk2(b.z, b.w);
        }
        *(uint4*)(As + row * 128 + ((q ^ (row & 7)) << 3)) = v;
    }
    const uint4* wsrc = (const uint4*)(wt1 + (size_t)conv * 32768);
#pragma unroll
    for (int p = 0; p < 16; ++p) {
        int id = p * 256 + t;
        *(uint4*)(Ws + (size_t)id * 8) = wsrc[id];
    }
    __syncthreads();

    f32x4 acc[4][4];
#pragma unroll
    for (int mt = 0; mt < 4; ++mt)
#pragma unroll
        for (int nt = 0; nt < 4; ++nt) acc[mt][nt] = (f32x4){0.f, 0.f, 0.f, 0.f};

    int lr = l & 15, lg = l >> 4;
#pragma unroll
    for (int s = 0; s < 4; ++s) {
        int kq = s * 4 + lg;
        bf16x8 af[4], bf[4];
#pragma unroll
        for (int mt = 0; mt < 4; ++mt) {
            int r = mt * 16 + lr;
            af[mt] = *(const bf16x8*)(As + r * 128 + ((kq ^ (r & 7)) << 3));
        }
#pragma unroll
        for (int nt = 0; nt < 4; ++nt) {
            int c = w * 64 + nt * 16 + lr;
            bf[nt] = *(const bf16x8*)(Ws + c * 128 + ((kq ^ (c & 7)) << 3));
        }
#pragma unroll
        for (int mt = 0; mt < 4; ++mt)
#pragma unroll
            for (int nt = 0; nt < 4; ++nt)
                acc[mt][nt] = __builtin_amdgcn_mfma_f32_16x16x32_bf16(af[mt], bf[nt], acc[mt][nt], 0, 0, 0);
    }

    float aswv[4], adwv[4];
#pragma unroll
    for (int nt = 0; nt < 4; ++nt) {
        aswv[nt] = asw[conv * 256 + w * 64 + nt * 16 + lr];
        adwv[nt] = adw[conv * 256 + w * 64 + nt * 16 + lr];
    }
#pragma unroll
    for (int mt = 0; mt < 4; ++mt) {
#pragma unroll
        for (int i = 0; i < 4; ++i) {
            int grow = blockIdx.x * 64 + mt * 16 + lg * 4 + i;
            bool ok = grow < N;
            float sv = 0.f, dv = 0.f;
#pragma unroll
            for (int nt = 0; nt < 4; ++nt) {
                float hv = acc[mt][nt][i];
                if (ok) hp[((size_t)conv * N + grow) * 256 + (nt * 16 + lr) * 4 + w] = f2bf(hv);
                sv += hv * aswv[nt];
                dv += hv * adwv[nt];
            }
#pragma unroll
            for (int o = 1; o < 16; o <<= 1) {
                sv += __shfl_xor(sv, o);
                dv += __shfl_xor(dv, o);
            }
            if (lr == 0 && ok) {
                as1[((size_t)conv * N + grow) * 4 + w] = sv;
                ad1[((size_t)conv * N + grow) * 4 + w] = dv;
            }
        }
    }
}

// ---------------- layer-1 aggregate: XCD channel-sliced, inline softmax ----------------
// one launch per conv; slice = blockIdx.x & 7 -> XCD; wave = (node, slice)
// lane = eo*4 + ci: eo = edge offset (16 edges/iter), ci = 16B chunk (2 c x 4 heads)

__global__ __launch_bounds__(256) void agg1_slice(const unsigned short* __restrict__ hpk,
                                                  const float* __restrict__ as1k, const float* __restrict__ ad1k,
                                                  const int* __restrict__ off, const int* __restrict__ srcs,
                                                  const float* __restrict__ b1k,
                                                  unsigned short* __restrict__ x2, int conv, int N) {
    int slice = blockIdx.x & 7;
    int n = (blockIdx.x >> 3) * 4 + (threadIdx.x >> 6);
    if (n >= N) return;
    int lane = threadIdx.x & 63;
    int eo = lane >> 2, ci = lane & 3;
    int r0 = off[n], r1 = off[n + 1];

    float4 adn = *(const float4*)(ad1k + (size_t)n * 4);

    float acc[8] = {0.f, 0.f, 0.f, 0.f, 0.f, 0.f, 0.f, 0.f};   // [c2][head]
    float den[4] = {0.f, 0.f, 0.f, 0.f};

    for (int base = r0; base + eo < r1; base += 16) {
        int e = base + eo;
        int s = __builtin_nontemporal_load(srcs + e);
        float4 av = *(const float4*)(as1k + (size_t)s * 4);
        uint4 g = *(const uint4*)(hpk + (size_t)s * 256 + slice * 32 + ci * 8);
        float p0 = __expf(LEAKY(av.x + adn.x));
        float p1 = __expf(LEAKY(av.y + adn.y));
        float p2 = __expf(LEAKY(av.z + adn.z));
        float p3 = __expf(LEAKY(av.w + adn.w));
        den[0] += p0; den[1] += p1; den[2] += p2; den[3] += p3;
        acc[0] += p0 * lo16(g.x); acc[1] += p1 * hi16(g.x);
        acc[2] += p2 * lo16(g.y); acc[3] += p3 * hi16(g.y);
        acc[4] += p0 * lo16(g.z); acc[5] += p1 * hi16(g.z);
        acc[6] += p2 * lo16(g.w); acc[7] += p3 * hi16(g.w);
    }

#pragma unroll
    for (int o = 4; o < 64; o <<= 1) {
#pragma unroll
        for (int j = 0; j < 8; ++j) acc[j] += __shfl_xor(acc[j], o);
#pragma unroll
        for (int j = 0; j < 4; ++j) den[j] += __shfl_xor(den[j], o);
    }

    if (eo == 0) {
        unsigned short* xo = x2 + (size_t)n * 512 + conv * 256;
#pragma unroll
        for (int c2 = 0; c2 < 2; ++c2) {
            int c = slice * 8 + ci * 2 + c2;
#pragma unroll
            for (int h = 0; h < 4; ++h) {
                float o = acc[c2 * 4 + h] / (den[h] + 1e-16f) + b1k[h * 64 + c];
                o = o > 0.f ? o : (__expf(o) - 1.0f);
                xo[h * 64 + c] = f2bf(o);
            }
        }
    }
}

// ---------------- GEMM2 MFMA: x2 [N,512] @ wt2 -> h2 [N,16] + fused alpha2 ----------------

__global__ __launch_bounds__(256) void gemm2_mfma(const unsigned short* __restrict__ x2,
                                                  const unsigned short* __restrict__ wt2,
                                                  const float* __restrict__ asw2, const float* __restrict__ adw2,
                                                  float* __restrict__ h2,
                                                  float* __restrict__ as2, float* __restrict__ ad2, int N) {
    int t = threadIdx.x;
    int w = t >> 6, l = t & 63;
    int rowbase = (blockIdx.x * 4 + w) * 16;
    if (rowbase >= N) return;
    int lr = l & 15, lg = l >> 4;

    f32x4 acc = (f32x4){0.f, 0.f, 0.f, 0.f};
    const unsigned short* ap = x2 + (size_t)(rowbase + lr) * 512 + lg * 8;
#pragma unroll
    for (int s = 0; s < 16; ++s) {
        bf16x8 av = *(const bf16x8*)(ap + s * 32);
        bf16x8 bv = *(const bf16x8*)(wt2 + ((size_t)s * 64 + l) * 8);
        acc = __builtin_amdgcn_mfma_f32_16x16x32_bf16(av, bv, acc, 0, 0, 0);
    }

    float asv = asw2[lr], adv = adw2[lr];
#pragma unroll
    for (int i = 0; i < 4; ++i) {
        int row = rowbase + lg * 4 + i;
        if (row < N) h2[(size_t)row * 16 + lr] = acc[i];
        float sv = acc[i] * asv, dv = acc[i] * adv;
#pragma unroll
        for (int o = 1; o < 16; o <<= 1) {
            sv += __shfl_xor(sv, o);
            dv += __shfl_xor(dv, o);
        }
        if (lr == 0 && row < N) { as2[row] = sv; ad2[row] = dv; }
    }
}

// ---------------- layer-2 aggregate, inline softmax -> out ----------------

__global__ __launch_bounds__(256) void agg2(const float* __restrict__ h2,
                                            const float* __restrict__ as2, const float* __restrict__ ad2,
                                            const int* __restrict__ off, const int* __restrict__ srcs,
                                            const float* __restrict__ bias2, float* __restrict__ out, int N) {
    int n = blockIdx.x * 4 + (threadIdx.x >> 6);
    int lane = threadIdx.x & 63;
    if (n >= N) return;
    int r0 = off[n], r1 = off[n + 1];
    float adn = ad2[n];

    int c = lane & 15, q = lane >> 4;
    float acc = 0.f, denom = 0.f;
    for (int e = r0 + q; e < r1; e += 4) {
        int s = __builtin_nontemporal_load(srcs + e);
        float p = __expf(LEAKY(as2[s] + adn));
        denom += p;
        acc += p * h2[(size_t)s * 16 + c];
    }
    acc += __shfl_xor(acc, 16);     acc += __shfl_xor(acc, 32);
    denom += __shfl_xor(denom, 16); denom += __shfl_xor(denom, 32);
    if (lane < 16) out[(size_t)n * 16 + c] = acc / (denom + 1e-16f) + bias2[c];
}

// ---------------- launch ----------------

extern "C" void kernel_launch(void* const* d_in, const int* in_sizes, int n_in,
                              void* d_out, int out_size, void* d_ws, size_t ws_size,
                              hipStream_t stream) {
    const float* x_list = (const float*)d_in[0];   // [2, N, 128]
    const int*   ei     = (const int*)d_in[1];     // [2, E] int32
    const float* W1     = (const float*)d_in[2];   // [2, 128, 256]
    const float* as1w   = (const float*)d_in[3];   // [2, 4, 64]
    const float* ad1w   = (const float*)d_in[4];
    const float* b1     = (const float*)d_in[5];   // [2, 256]
    const float* W2     = (const float*)d_in[6];   // [512, 16]
    const float* as2w   = (const float*)d_in[7];
    const float* ad2w   = (const float*)d_in[8];
    const float* b2     = (const float*)d_in[9];   // [16]
    float* out = (float*)d_out;

    const int N = in_sizes[0] / 256;   // 50000
    const int E = in_sizes[1] / 2;     // 800000
    const int Etot = E + N;

    char* ws = (char*)d_ws;
    size_t woff = 0;
    auto alloc = [&](size_t bytes) {
        char* p = ws + woff;
        woff = (woff + bytes + 255) & ~(size_t)255;
        return p;
    };
    int*   csr    = (int*)alloc((size_t)(N + 1) * 4);
    int*   cursor = (int*)alloc((size_t)N * 4);
    int*   srcs   = (int*)alloc((size_t)Etot * 4);
    int*   bsum   = (int*)alloc(512 * 4);
    int*   boff   = (int*)alloc(512 * 4);
    float* as1    = (float*)alloc((size_t)N * 4 * 2 * 4);   // [2][N][4]
    float* ad1    = (float*)alloc((size_t)N * 4 * 2 * 4);
    float* as2    = (float*)alloc((size_t)N * 4);
    float* ad2    = (float*)alloc((size_t)N * 4);
    unsigned short* wt1 = (unsigned short*)alloc(2 * 32768 * 2);
    unsigned short* wt2 = (unsigned short*)alloc(16 * 64 * 8 * 2);
    unsigned short* hp  = (unsigned short*)alloc((size_t)N * 256 * 2 * 2); // [2][N][64][4] bf16
    unsigned short* x2  = (unsigned short*)alloc((size_t)N * 512 * 2);     // bf16
    float* h2     = (float*)alloc((size_t)N * 16 * 4);

    // CSR by dst
    hipMemsetAsync(cursor, 0, (size_t)N * 4, stream);
    int gE = (Etot + 255) / 256;
    count_deg<<<gE, 256, 0, stream>>>(ei, cursor, E, Etot);
    int nb = (N + 511) / 512;
    scan_block<<<nb, 512, 0, stream>>>(cursor, csr, bsum, N);
    scan_sums<<<1, 512, 0, stream>>>(bsum, boff, nb);
    finalize_off<<<(N + 255) / 256, 256, 0, stream>>>(csr, cursor, boff, N, Etot);
    scatter_src<<<gE, 256, 0, stream>>>(ei, cursor, srcs, E, Etot);

    wpack1<<<32, 256, 0, stream>>>(W1, wt1);
    wpack2<<<4, 256, 0, stream>>>(W2, wt2);

    // layer 1
    gemm1_mfma<<<dim3((N + 63) / 64, 2), 256, 0, stream>>>(x_list, wt1, as1w, ad1w, hp, as1, ad1, N);
    int gAgg = 8 * ((N + 3) / 4);
    for (int k = 0; k < 2; ++k)
        agg1_slice<<<gAgg, 256, 0, stream>>>(hp + (size_t)k * N * 256,
                                             as1 + (size_t)k * N * 4, ad1 + (size_t)k * N * 4,
                                             csr, srcs, b1 + k * 256, x2, k, N);

    // layer 2
    gemm2_mfma<<<(N + 63) / 64, 256, 0, stream>>>(x2, wt2, as2w, ad2w, h2, as2, ad2, N);
    agg2<<<(N + 3) / 4, 256, 0, stream>>>(h2, as2, ad2, csr, srcs, b2, out, N);
}

// Round 7
// 351.699 us; speedup vs baseline: 1.9165x; 1.9165x over previous
//
#include <hip/hip_runtime.h>

#define LEAKY(v) ((v) >= 0.0f ? (v) : 0.2f * (v))

typedef __attribute__((ext_vector_type(8))) short bf16x8;
typedef __attribute__((ext_vector_type(4))) float f32x4;

__device__ __forceinline__ unsigned short f2bf(float f) {
    unsigned int u = __float_as_uint(f);
    unsigned int r = u + 0x7FFFu + ((u >> 16) & 1u);
    return (unsigned short)(r >> 16);
}
__device__ __forceinline__ unsigned int pk2(float a, float b) {
    return (unsigned int)f2bf(a) | ((unsigned int)f2bf(b) << 16);
}
__device__ __forceinline__ float lo16(unsigned int u) { return __uint_as_float(u << 16); }
__device__ __forceinline__ float hi16(unsigned int u) { return __uint_as_float(u & 0xFFFF0000u); }

// ---------------- CSR build ----------------

__global__ __launch_bounds__(256) void count_deg(const int* ei, int* deg, int E, int Etot) {
    int i = blockIdx.x * 256 + threadIdx.x;
    if (i >= Etot) return;
    int d = (i < E) ? ei[E + i] : (i - E);
    atomicAdd(&deg[d], 1);
}

__global__ __launch_bounds__(512) void scan_block(const int* deg, int* excl, int* bsum, int n) {
    __shared__ int s[512];
    int t = threadIdx.x;
    int i = blockIdx.x * 512 + t;
    int v = (i < n) ? deg[i] : 0;
    s[t] = v;
    __syncthreads();
    for (int d = 1; d < 512; d <<= 1) {
        int x = 0;
        if (t >= d) x = s[t - d];
        __syncthreads();
        if (t >= d) s[t] += x;
        __syncthreads();
    }
    if (i < n) excl[i] = s[t] - v;
    if (t == 511) bsum[blockIdx.x] = s[511];
}

__global__ __launch_bounds__(512) void scan_sums(const int* bsum, int* boff, int nb) {
    __shared__ int s[512];
    int t = threadIdx.x;
    int v = (t < nb) ? bsum[t] : 0;
    s[t] = v;
    __syncthreads();
    for (int d = 1; d < 512; d <<= 1) {
        int x = 0;
        if (t >= d) x = s[t - d];
        __syncthreads();
        if (t >= d) s[t] += x;
        __syncthreads();
    }
    boff[t] = s[t] - v;
}

__global__ __launch_bounds__(256) void finalize_off(int* csr, int* cursor, const int* boff, int n, int etot) {
    int i = blockIdx.x * 256 + threadIdx.x;
    if (i < n) {
        int v = csr[i] + boff[i >> 9];
        csr[i] = v;
        cursor[i] = v;
    }
    if (i == 0) csr[n] = etot;
}

__global__ __launch_bounds__(256) void scatter_edge(const int* ei, int* cursor, int* srcs, int* dsts,
                                                    int E, int Etot) {
    int i = blockIdx.x * 256 + threadIdx.x;
    if (i >= Etot) return;
    int s, d;
    if (i < E) { s = ei[i]; d = ei[E + i]; }
    else       { s = i - E; d = s; }
    int pos = atomicAdd(&cursor[d], 1);
    srcs[pos] = s;
    dsts[pos] = d;
}

// ---------------- weight packing ----------------

// W1 (f32 [2][128][256]) -> wt1 (bf16 [2][256 c][128 k], transposed, swizzle baked)
__global__ __launch_bounds__(256) void wpack1(const float* __restrict__ W1, unsigned short* __restrict__ wt1) {
    int id = blockIdx.x * 256 + threadIdx.x;      // conv*4096 + c*16 + q
    if (id >= 8192) return;
    int conv = id >> 12, rem = id & 4095;
    int c = rem >> 4, q = rem & 15;
    const float* src = W1 + (size_t)conv * 32768 + (size_t)(q * 8) * 256 + c;
    float w[8];
#pragma unroll
    for (int j = 0; j < 8; ++j) w[j] = src[j * 256];
    uint4 v;
    v.x = pk2(w[0], w[1]); v.y = pk2(w[2], w[3]);
    v.z = pk2(w[4], w[5]); v.w = pk2(w[6], w[7]);
    *(uint4*)(wt1 + (size_t)conv * 32768 + c * 128 + ((q ^ (c & 7)) << 3)) = v;
}

// W2 (f32 [512][16]) -> wt2 (bf16 B-fragment image [16 steps][64 lanes][8])
__global__ __launch_bounds__(256) void wpack2(const float* __restrict__ W2, unsigned short* __restrict__ wt2) {
    int id = blockIdx.x * 256 + threadIdx.x;      // s*64 + l
    if (id >= 1024) return;
    int s = id >> 6, l = id & 63;
    const float* src = W2 + (size_t)(s * 32 + (l >> 4) * 8) * 16 + (l & 15);
    float w[8];
#pragma unroll
    for (int j = 0; j < 8; ++j) w[j] = src[j * 16];
    uint4 v;
    v.x = pk2(w[0], w[1]); v.y = pk2(w[2], w[3]);
    v.z = pk2(w[4], w[5]); v.w = pk2(w[6], w[7]);
    *(uint4*)(wt2 + (size_t)id * 8) = v;
}

// ---------------- GEMM1 MFMA (fused f32->bf16 staging + fused alpha) ----------------
// block: 64 rows x 256 cols; 4 waves, wave w = head w
// hp layout: [n][c(64)][conv(2)][head(4)] bf16  (1 KB per node)

__global__ __launch_bounds__(256) void gemm1_mfma(const float* __restrict__ x_list,
                                                  const unsigned short* __restrict__ wt1,
                                                  const float* __restrict__ asw, const float* __restrict__ adw,
                                                  unsigned short* __restrict__ hp,
                                                  float* __restrict__ as1, float* __restrict__ ad1, int N) {
    __shared__ unsigned short As[64 * 128];    // 16 KB swizzled
    __shared__ unsigned short Ws[256 * 128];   // 64 KB swizzled
    int conv = blockIdx.y;
    int t = threadIdx.x;
    int w = t >> 6, l = t & 63;

    const float* xg = x_list + (size_t)conv * N * 128;
#pragma unroll
    for (int p = 0; p < 4; ++p) {
        int id = p * 256 + t;
        int row = id >> 4, q = id & 15;
        int grow = blockIdx.x * 64 + row;
        uint4 v = make_uint4(0, 0, 0, 0);
        if (grow < N) {
            const float* src = xg + (size_t)grow * 128 + q * 8;
            float4 a = *(const float4*)src;
            float4 b = *(const float4*)(src + 4);
            v.x = pk2(a.x, a.y); v.y = pk2(a.z, a.w);
            v.z = pk2(b.x, b.y); v.w = pk2(b.z, b.w);
        }
        *(uint4*)(As + row * 128 + ((q ^ (row & 7)) << 3)) = v;
    }
    const uint4* wsrc = (const uint4*)(wt1 + (size_t)conv * 32768);
#pragma unroll
    for (int p = 0; p < 16; ++p) {
        int id = p * 256 + t;
        *(uint4*)(Ws + (size_t)id * 8) = wsrc[id];
    }
    __syncthreads();

    f32x4 acc[4][4];
#pragma unroll
    for (int mt = 0; mt < 4; ++mt)
#pragma unroll
        for (int nt = 0; nt < 4; ++nt) acc[mt][nt] = (f32x4){0.f, 0.f, 0.f, 0.f};

    int lr = l & 15, lg = l >> 4;
#pragma unroll
    for (int s = 0; s < 4; ++s) {
        int kq = s * 4 + lg;
        bf16x8 af[4], bf[4];
#pragma unroll
        for (int mt = 0; mt < 4; ++mt) {
            int r = mt * 16 + lr;
            af[mt] = *(const bf16x8*)(As + r * 128 + ((kq ^ (r & 7)) << 3));
        }
#pragma unroll
        for (int nt = 0; nt < 4; ++nt) {
            int c = w * 64 + nt * 16 + lr;
            bf[nt] = *(const bf16x8*)(Ws + c * 128 + ((kq ^ (c & 7)) << 3));
        }
#pragma unroll
        for (int mt = 0; mt < 4; ++mt)
#pragma unroll
            for (int nt = 0; nt < 4; ++nt)
                acc[mt][nt] = __builtin_amdgcn_mfma_f32_16x16x32_bf16(af[mt], bf[nt], acc[mt][nt], 0, 0, 0);
    }

    float aswv[4], adwv[4];
#pragma unroll
    for (int nt = 0; nt < 4; ++nt) {
        aswv[nt] = asw[conv * 256 + w * 64 + nt * 16 + lr];
        adwv[nt] = adw[conv * 256 + w * 64 + nt * 16 + lr];
    }
#pragma unroll
    for (int mt = 0; mt < 4; ++mt) {
#pragma unroll
        for (int i = 0; i < 4; ++i) {
            int grow = blockIdx.x * 64 + mt * 16 + lg * 4 + i;
            bool ok = grow < N;
            float sv = 0.f, dv = 0.f;
#pragma unroll
            for (int nt = 0; nt < 4; ++nt) {
                float hv = acc[mt][nt][i];
                if (ok) hp[(size_t)grow * 512 + (nt * 16 + lr) * 8 + conv * 4 + w] = f2bf(hv);
                sv += hv * aswv[nt];
                dv += hv * adwv[nt];
            }
#pragma unroll
            for (int o = 1; o < 16; o <<= 1) {
                sv += __shfl_xor(sv, o);
                dv += __shfl_xor(dv, o);
            }
            if (lr == 0 && ok) {
                as1[((size_t)conv * N + grow) * 4 + w] = sv;
                ad1[((size_t)conv * N + grow) * 4 + w] = dv;
            }
        }
    }
}

// ---------------- edge-parallel softmax weights, layer 1 (both convs) ----------------

__global__ __launch_bounds__(256) void edge_w1(const int* __restrict__ srcs, const int* __restrict__ dsts,
                                               const float* __restrict__ as, const float* __restrict__ ad,
                                               float* __restrict__ pw, int Etot, int N4) {
    int e = blockIdx.x * 256 + threadIdx.x;
    if (e >= Etot) return;
    int s = srcs[e], d = dsts[e];
    float4 a0 = *(const float4*)(as + (size_t)s * 4);
    float4 b0 = *(const float4*)(ad + (size_t)d * 4);
    float4 a1 = *(const float4*)(as + N4 + (size_t)s * 4);
    float4 b1 = *(const float4*)(ad + N4 + (size_t)d * 4);
    float4 p0, p1;
    p0.x = __expf(LEAKY(a0.x + b0.x));
    p0.y = __expf(LEAKY(a0.y + b0.y));
    p0.z = __expf(LEAKY(a0.z + b0.z));
    p0.w = __expf(LEAKY(a0.w + b0.w));
    p1.x = __expf(LEAKY(a1.x + b1.x));
    p1.y = __expf(LEAKY(a1.y + b1.y));
    p1.z = __expf(LEAKY(a1.z + b1.z));
    p1.w = __expf(LEAKY(a1.w + b1.w));
    *(float4*)(pw + (size_t)e * 8)     = p0;
    *(float4*)(pw + (size_t)e * 8 + 4) = p1;
}

// ---------------- layer-1 aggregate: packed 16B gather, shfl-broadcast srcs ----------------

#define ACC8(g, pa, pb) {                                                      \
    den[0] += (pa).x; acc[0] += (pa).x * lo16((g).x);                          \
    den[1] += (pa).y; acc[1] += (pa).y * hi16((g).x);                          \
    den[2] += (pa).z; acc[2] += (pa).z * lo16((g).y);                          \
    den[3] += (pa).w; acc[3] += (pa).w * hi16((g).y);                          \
    den[4] += (pb).x; acc[4] += (pb).x * lo16((g).z);                          \
    den[5] += (pb).y; acc[5] += (pb).y * hi16((g).z);                          \
    den[6] += (pb).z; acc[6] += (pb).z * lo16((g).w);                          \
    den[7] += (pb).w; acc[7] += (pb).w * hi16((g).w); }

__global__ __launch_bounds__(256) void agg1_both(const unsigned short* __restrict__ hp,
                                                 const float* __restrict__ pw,
                                                 const int* __restrict__ off, const int* __restrict__ srcs,
                                                 const float* __restrict__ b1,
                                                 unsigned short* __restrict__ x2, int N) {
    int n = blockIdx.x * 4 + (threadIdx.x >> 6);
    int lane = threadIdx.x & 63;
    if (n >= N) return;
    int r0 = off[n], r1 = off[n + 1];

    float acc[8] = {0.f, 0.f, 0.f, 0.f, 0.f, 0.f, 0.f, 0.f};
    float den[8] = {0.f, 0.f, 0.f, 0.f, 0.f, 0.f, 0.f, 0.f};

    for (int base = r0; base < r1; base += 64) {
        int cnt = min(64, r1 - base);
        int my = (base + lane < r1) ? __builtin_nontemporal_load(srcs + base + lane) : 0;
        int j = 0;
        for (; j + 4 <= cnt; j += 4) {
            int s0 = __shfl(my, j);
            int s1 = __shfl(my, j + 1);
            int s2 = __shfl(my, j + 2);
            int s3 = __shfl(my, j + 3);
            uint4 g0 = *(const uint4*)(hp + (size_t)s0 * 512 + lane * 8);
            uint4 g1 = *(const uint4*)(hp + (size_t)s1 * 512 + lane * 8);
            uint4 g2 = *(const uint4*)(hp + (size_t)s2 * 512 + lane * 8);
            uint4 g3 = *(const uint4*)(hp + (size_t)s3 * 512 + lane * 8);
            f32x4 pa0 = __builtin_nontemporal_load((const f32x4*)(pw + (size_t)(base + j) * 8));
            f32x4 pb0 = __builtin_nontemporal_load((const f32x4*)(pw + (size_t)(base + j) * 8 + 4));
            f32x4 pa1 = __builtin_nontemporal_load((const f32x4*)(pw + (size_t)(base + j + 1) * 8));
            f32x4 pb1 = __builtin_nontemporal_load((const f32x4*)(pw + (size_t)(base + j + 1) * 8 + 4));
            f32x4 pa2 = __builtin_nontemporal_load((const f32x4*)(pw + (size_t)(base + j + 2) * 8));
            f32x4 pb2 = __builtin_nontemporal_load((const f32x4*)(pw + (size_t)(base + j + 2) * 8 + 4));
            f32x4 pa3 = __builtin_nontemporal_load((const f32x4*)(pw + (size_t)(base + j + 3) * 8));
            f32x4 pb3 = __builtin_nontemporal_load((const f32x4*)(pw + (size_t)(base + j + 3) * 8 + 4));
            ACC8(g0, pa0, pb0);
            ACC8(g1, pa1, pb1);
            ACC8(g2, pa2, pb2);
            ACC8(g3, pa3, pb3);
        }
        for (; j < cnt; ++j) {
            int s0 = __shfl(my, j);
            uint4 g0 = *(const uint4*)(hp + (size_t)s0 * 512 + lane * 8);
            f32x4 pa0 = __builtin_nontemporal_load((const f32x4*)(pw + (size_t)(base + j) * 8));
            f32x4 pb0 = __builtin_nontemporal_load((const f32x4*)(pw + (size_t)(base + j) * 8 + 4));
            ACC8(g0, pa0, pb0);
        }
    }

    unsigned short* xo = x2 + (size_t)n * 512;
#pragma unroll
    for (int q = 0; q < 8; ++q) {
        int k = q >> 2, hd = q & 3;
        int ofs = k * 256 + hd * 64 + lane;
        float o = acc[q] / (den[q] + 1e-16f) + b1[ofs];
        o = o > 0.f ? o : (__expf(o) - 1.0f);
        xo[ofs] = f2bf(o);
    }
}

// ---------------- GEMM2 MFMA: x2 [N,512] @ wt2 -> h2 [N,16] + fused alpha2 ----------------

__global__ __launch_bounds__(256) void gemm2_mfma(const unsigned short* __restrict__ x2,
                                                  const unsigned short* __restrict__ wt2,
                                                  const float* __restrict__ asw2, const float* __restrict__ adw2,
                                                  float* __restrict__ h2,
                                                  float* __restrict__ as2, float* __restrict__ ad2, int N) {
    int t = threadIdx.x;
    int w = t >> 6, l = t & 63;
    int rowbase = (blockIdx.x * 4 + w) * 16;
    if (rowbase >= N) return;
    int lr = l & 15, lg = l >> 4;

    f32x4 acc = (f32x4){0.f, 0.f, 0.f, 0.f};
    const unsigned short* ap = x2 + (size_t)(rowbase + lr) * 512 + lg * 8;
#pragma unroll
    for (int s = 0; s < 16; ++s) {
        bf16x8 av = *(const bf16x8*)(ap + s * 32);
        bf16x8 bv = *(const bf16x8*)(wt2 + ((size_t)s * 64 + l) * 8);
        acc = __builtin_amdgcn_mfma_f32_16x16x32_bf16(av, bv, acc, 0, 0, 0);
    }

    float asv = asw2[lr], adv = adw2[lr];
#pragma unroll
    for (int i = 0; i < 4; ++i) {
        int row = rowbase + lg * 4 + i;
        if (row < N) h2[(size_t)row * 16 + lr] = acc[i];
        float sv = acc[i] * asv, dv = acc[i] * adv;
#pragma unroll
        for (int o = 1; o < 16; o <<= 1) {
            sv += __shfl_xor(sv, o);
            dv += __shfl_xor(dv, o);
        }
        if (lr == 0 && row < N) { as2[row] = sv; ad2[row] = dv; }
    }
}

// ---------------- layer-2 aggregate, inline softmax, 16 edges in flight -> out ----------------

__global__ __launch_bounds__(256) void agg2(const float* __restrict__ h2,
                                            const float* __restrict__ as2, const float* __restrict__ ad2,
                                            const int* __restrict__ off, const int* __restrict__ srcs,
                                            const float* __restrict__ bias2, float* __restrict__ out, int N) {
    int n = blockIdx.x * 4 + (threadIdx.x >> 6);
    int lane = threadIdx.x & 63;
    if (n >= N) return;
    int r0 = off[n], r1 = off[n + 1];
    float adn = ad2[n];
    int cg = lane & 3, eo = lane >> 2;   // 16 edges in flight x 4 channel-groups

    float4 acc = make_float4(0.f, 0.f, 0.f, 0.f);
    float den = 0.f;
    for (int base = r0; base + eo < r1; base += 16) {
        int e = base + eo;
        int s = __builtin_nontemporal_load(srcs + e);
        float p = __expf(LEAKY(as2[s] + adn));
        float4 hv = *(const float4*)(h2 + (size_t)s * 16 + cg * 4);
        den += p;
        acc.x += p * hv.x; acc.y += p * hv.y;
        acc.z += p * hv.z; acc.w += p * hv.w;
    }
#pragma unroll
    for (int o = 4; o < 64; o <<= 1) {
        acc.x += __shfl_xor(acc.x, o);
        acc.y += __shfl_xor(acc.y, o);
        acc.z += __shfl_xor(acc.z, o);
        acc.w += __shfl_xor(acc.w, o);
        den   += __shfl_xor(den, o);
    }
    if (eo == 0) {
        float inv = 1.f / (den + 1e-16f);
        float4 b = *(const float4*)(bias2 + cg * 4);
        float4 o4;
        o4.x = acc.x * inv + b.x;
        o4.y = acc.y * inv + b.y;
        o4.z = acc.z * inv + b.z;
        o4.w = acc.w * inv + b.w;
        *(float4*)(out + (size_t)n * 16 + cg * 4) = o4;
    }
}

// ---------------- launch ----------------

extern "C" void kernel_launch(void* const* d_in, const int* in_sizes, int n_in,
                              void* d_out, int out_size, void* d_ws, size_t ws_size,
                              hipStream_t stream) {
    const float* x_list = (const float*)d_in[0];   // [2, N, 128]
    const int*   ei     = (const int*)d_in[1];     // [2, E] int32
    const float* W1     = (const float*)d_in[2];   // [2, 128, 256]
    const float* as1w   = (const float*)d_in[3];   // [2, 4, 64]
    const float* ad1w   = (const float*)d_in[4];
    const float* b1     = (const float*)d_in[5];   // [2, 256]
    const float* W2     = (const float*)d_in[6];   // [512, 16]
    const float* as2w   = (const float*)d_in[7];
    const float* ad2w   = (const float*)d_in[8];
    const float* b2     = (const float*)d_in[9];   // [16]
    float* out = (float*)d_out;

    const int N = in_sizes[0] / 256;   // 50000
    const int E = in_sizes[1] / 2;     // 800000
    const int Etot = E + N;
    const int N4 = N * 4;

    char* ws = (char*)d_ws;
    size_t woff = 0;
    auto alloc = [&](size_t bytes) {
        char* p = ws + woff;
        woff = (woff + bytes + 255) & ~(size_t)255;
        return p;
    };
    int*   csr    = (int*)alloc((size_t)(N + 1) * 4);
    int*   cursor = (int*)alloc((size_t)N * 4);
    int*   srcs   = (int*)alloc((size_t)Etot * 4);
    int*   dsts   = (int*)alloc((size_t)Etot * 4);
    int*   bsum   = (int*)alloc(512 * 4);
    int*   boff   = (int*)alloc(512 * 4);
    float* as1    = (float*)alloc((size_t)N4 * 2 * 4);   // [2][N][4]
    float* ad1    = (float*)alloc((size_t)N4 * 2 * 4);
    float* as2    = (float*)alloc((size_t)N * 4);
    float* ad2    = (float*)alloc((size_t)N * 4);
    unsigned short* wt1 = (unsigned short*)alloc(2 * 32768 * 2);
    unsigned short* wt2 = (unsigned short*)alloc(16 * 64 * 8 * 2);
    unsigned short* hp  = (unsigned short*)alloc((size_t)N * 512 * 2);   // [n][64][2][4] bf16, 51.2 MB
    unsigned short* x2  = (unsigned short*)alloc((size_t)N * 512 * 2);   // bf16, 51.2 MB
    float* h2     = (float*)alloc((size_t)N * 16 * 4);
    float* pw     = (float*)alloc((size_t)Etot * 8 * 4);  // 27.2 MB

    // CSR by dst
    hipMemsetAsync(cursor, 0, (size_t)N * 4, stream);
    int gE = (Etot + 255) / 256;
    count_deg<<<gE, 256, 0, stream>>>(ei, cursor, E, Etot);
    int nb = (N + 511) / 512;
    scan_block<<<nb, 512, 0, stream>>>(cursor, csr, bsum, N);
    scan_sums<<<1, 512, 0, stream>>>(bsum, boff, nb);
    finalize_off<<<(N + 255) / 256, 256, 0, stream>>>(csr, cursor, boff, N, Etot);
    scatter_edge<<<gE, 256, 0, stream>>>(ei, cursor, srcs, dsts, E, Etot);

    wpack1<<<32, 256, 0, stream>>>(W1, wt1);
    wpack2<<<4, 256, 0, stream>>>(W2, wt2);

    // layer 1
    gemm1_mfma<<<dim3((N + 63) / 64, 2), 256, 0, stream>>>(x_list, wt1, as1w, ad1w, hp, as1, ad1, N);
    edge_w1<<<gE, 256, 0, stream>>>(srcs, dsts, as1, ad1, pw, Etot, N4);
    agg1_both<<<(N + 3) / 4, 256, 0, stream>>>(hp, pw, csr, srcs, b1, x2, N);

    // layer 2
    gemm2_mfma<<<(N + 63) / 64, 256, 0, stream>>>(x2, wt2, as2w, ad2w, h2, as2, ad2, N);
    agg2<<<(N + 3) / 4, 256, 0, stream>>>(h2, as2, ad2, csr, srcs, b2, out, N);
}

// Round 8
// 328.433 us; speedup vs baseline: 2.0522x; 1.0708x over previous
//
#include <hip/hip_runtime.h>

#define LEAKY(v) ((v) >= 0.0f ? (v) : 0.2f * (v))

typedef __attribute__((ext_vector_type(8))) short bf16x8;
typedef __attribute__((ext_vector_type(4))) float f32x4;

__device__ __forceinline__ unsigned short f2bf(float f) {
    unsigned int u = __float_as_uint(f);
    unsigned int r = u + 0x7FFFu + ((u >> 16) & 1u);
    return (unsigned short)(r >> 16);
}
__device__ __forceinline__ unsigned int pk2(float a, float b) {
    return (unsigned int)f2bf(a) | ((unsigned int)f2bf(b) << 16);
}
__device__ __forceinline__ float lo16(unsigned int u) { return __uint_as_float(u << 16); }
__device__ __forceinline__ float hi16(unsigned int u) { return __uint_as_float(u & 0xFFFF0000u); }

// ---------------- CSR build ----------------

__global__ __launch_bounds__(256) void count_deg(const int* ei, int* deg, int E, int Etot) {
    int i = blockIdx.x * 256 + threadIdx.x;
    if (i >= Etot) return;
    int d = (i < E) ? ei[E + i] : (i - E);
    atomicAdd(&deg[d], 1);
}

__global__ __launch_bounds__(512) void scan_block(const int* deg, int* excl, int* bsum, int n) {
    __shared__ int s[512];
    int t = threadIdx.x;
    int i = blockIdx.x * 512 + t;
    int v = (i < n) ? deg[i] : 0;
    s[t] = v;
    __syncthreads();
    for (int d = 1; d < 512; d <<= 1) {
        int x = 0;
        if (t >= d) x = s[t - d];
        __syncthreads();
        if (t >= d) s[t] += x;
        __syncthreads();
    }
    if (i < n) excl[i] = s[t] - v;
    if (t == 511) bsum[blockIdx.x] = s[511];
}

__global__ __launch_bounds__(512) void scan_sums(const int* bsum, int* boff, int nb) {
    __shared__ int s[512];
    int t = threadIdx.x;
    int v = (t < nb) ? bsum[t] : 0;
    s[t] = v;
    __syncthreads();
    for (int d = 1; d < 512; d <<= 1) {
        int x = 0;
        if (t >= d) x = s[t - d];
        __syncthreads();
        if (t >= d) s[t] += x;
        __syncthreads();
    }
    boff[t] = s[t] - v;
}

__global__ __launch_bounds__(256) void finalize_off(int* csr, int* cursor, const int* boff, int n, int etot) {
    int i = blockIdx.x * 256 + threadIdx.x;
    if (i < n) {
        int v = csr[i] + boff[i >> 9];
        csr[i] = v;
        cursor[i] = v;
    }
    if (i == 0) csr[n] = etot;
}

__global__ __launch_bounds__(256) void scatter_edge(const int* ei, int* cursor, int* srcs, int* dsts,
                                                    int E, int Etot) {
    int i = blockIdx.x * 256 + threadIdx.x;
    if (i >= Etot) return;
    int s, d;
    if (i < E) { s = ei[i]; d = ei[E + i]; }
    else       { s = i - E; d = s; }
    int pos = atomicAdd(&cursor[d], 1);
    srcs[pos] = s;
    dsts[pos] = d;
}

// ---------------- weight packing ----------------

// W1 (f32 [2][128][256]) -> wt1 (bf16 [2][256 c][128 k], transposed, swizzle baked)
__global__ __launch_bounds__(256) void wpack1(const float* __restrict__ W1, unsigned short* __restrict__ wt1) {
    int id = blockIdx.x * 256 + threadIdx.x;      // conv*4096 + c*16 + q
    if (id >= 8192) return;
    int conv = id >> 12, rem = id & 4095;
    int c = rem >> 4, q = rem & 15;
    const float* src = W1 + (size_t)conv * 32768 + (size_t)(q * 8) * 256 + c;
    float w[8];
#pragma unroll
    for (int j = 0; j < 8; ++j) w[j] = src[j * 256];
    uint4 v;
    v.x = pk2(w[0], w[1]); v.y = pk2(w[2], w[3]);
    v.z = pk2(w[4], w[5]); v.w = pk2(w[6], w[7]);
    *(uint4*)(wt1 + (size_t)conv * 32768 + c * 128 + ((q ^ (c & 7)) << 3)) = v;
}

// W2 (f32 [512][16]) -> wt2 (bf16 B-fragment image [16 steps][64 lanes][8])
__global__ __launch_bounds__(256) void wpack2(const float* __restrict__ W2, unsigned short* __restrict__ wt2) {
    int id = blockIdx.x * 256 + threadIdx.x;      // s*64 + l
    if (id >= 1024) return;
    int s = id >> 6, l = id & 63;
    const float* src = W2 + (size_t)(s * 32 + (l >> 4) * 8) * 16 + (l & 15);
    float w[8];
#pragma unroll
    for (int j = 0; j < 8; ++j) w[j] = src[j * 16];
    uint4 v;
    v.x = pk2(w[0], w[1]); v.y = pk2(w[2], w[3]);
    v.z = pk2(w[4], w[5]); v.w = pk2(w[6], w[7]);
    *(uint4*)(wt2 + (size_t)id * 8) = v;
}

// ---------------- GEMM1 MFMA (fused f32->bf16 staging + fused alpha) ----------------
// block: 64 rows x 256 cols; 4 waves, wave w = head w
// hp layout: [n][c(64)][conv(2)][head(4)] bf16  (1 KB per node)

__global__ __launch_bounds__(256) void gemm1_mfma(const float* __restrict__ x_list,
                                                  const unsigned short* __restrict__ wt1,
                                                  const float* __restrict__ asw, const float* __restrict__ adw,
                                                  unsigned short* __restrict__ hp,
                                                  float* __restrict__ as1, float* __restrict__ ad1, int N) {
    __shared__ unsigned short As[64 * 128];    // 16 KB swizzled
    __shared__ unsigned short Ws[256 * 128];   // 64 KB swizzled
    int conv = blockIdx.y;
    int t = threadIdx.x;
    int w = t >> 6, l = t & 63;

    const float* xg = x_list + (size_t)conv * N * 128;
#pragma unroll
    for (int p = 0; p < 4; ++p) {
        int id = p * 256 + t;
        int row = id >> 4, q = id & 15;
        int grow = blockIdx.x * 64 + row;
        uint4 v = make_uint4(0, 0, 0, 0);
        if (grow < N) {
            const float* src = xg + (size_t)grow * 128 + q * 8;
            float4 a = *(const float4*)src;
            float4 b = *(const float4*)(src + 4);
            v.x = pk2(a.x, a.y); v.y = pk2(a.z, a.w);
            v.z = pk2(b.x, b.y); v.w = pk2(b.z, b.w);
        }
        *(uint4*)(As + row * 128 + ((q ^ (row & 7)) << 3)) = v;
    }
    const uint4* wsrc = (const uint4*)(wt1 + (size_t)conv * 32768);
#pragma unroll
    for (int p = 0; p < 16; ++p) {
        int id = p * 256 + t;
        *(uint4*)(Ws + (size_t)id * 8) = wsrc[id];
    }
    __syncthreads();

    f32x4 acc[4][4];
#pragma unroll
    for (int mt = 0; mt < 4; ++mt)
#pragma unroll
        for (int nt = 0; nt < 4; ++nt) acc[mt][nt] = (f32x4){0.f, 0.f, 0.f, 0.f};

    int lr = l & 15, lg = l >> 4;
#pragma unroll
    for (int s = 0; s < 4; ++s) {
        int kq = s * 4 + lg;
        bf16x8 af[4], bf[4];
#pragma unroll
        for (int mt = 0; mt < 4; ++mt) {
            int r = mt * 16 + lr;
            af[mt] = *(const bf16x8*)(As + r * 128 + ((kq ^ (r & 7)) << 3));
        }
#pragma unroll
        for (int nt = 0; nt < 4; ++nt) {
            int c = w * 64 + nt * 16 + lr;
            bf[nt] = *(const bf16x8*)(Ws + c * 128 + ((kq ^ (c & 7)) << 3));
        }
#pragma unroll
        for (int mt = 0; mt < 4; ++mt)
#pragma unroll
            for (int nt = 0; nt < 4; ++nt)
                acc[mt][nt] = __builtin_amdgcn_mfma_f32_16x16x32_bf16(af[mt], bf[nt], acc[mt][nt], 0, 0, 0);
    }

    float aswv[4], adwv[4];
#pragma unroll
    for (int nt = 0; nt < 4; ++nt) {
        aswv[nt] = asw[conv * 256 + w * 64 + nt * 16 + lr];
        adwv[nt] = adw[conv * 256 + w * 64 + nt * 16 + lr];
    }
#pragma unroll
    for (int mt = 0; mt < 4; ++mt) {
#pragma unroll
        for (int i = 0; i < 4; ++i) {
            int grow = blockIdx.x * 64 + mt * 16 + lg * 4 + i;
            bool ok = grow < N;
            float sv = 0.f, dv = 0.f;
#pragma unroll
            for (int nt = 0; nt < 4; ++nt) {
                float hv = acc[mt][nt][i];
                if (ok) hp[(size_t)grow * 512 + (nt * 16 + lr) * 8 + conv * 4 + w] = f2bf(hv);
                sv += hv * aswv[nt];
                dv += hv * adwv[nt];
            }
#pragma unroll
            for (int o = 1; o < 16; o <<= 1) {
                sv += __shfl_xor(sv, o);
                dv += __shfl_xor(dv, o);
            }
            if (lr == 0 && ok) {
                as1[((size_t)conv * N + grow) * 4 + w] = sv;
                ad1[((size_t)conv * N + grow) * 4 + w] = dv;
            }
        }
    }
}

// ---------------- edge-parallel softmax weights, layer 1 (both convs) ----------------

__global__ __launch_bounds__(256) void edge_w1(const int* __restrict__ srcs, const int* __restrict__ dsts,
                                               const float* __restrict__ as, const float* __restrict__ ad,
                                               float* __restrict__ pw, int Etot, int N4) {
    int e = blockIdx.x * 256 + threadIdx.x;
    if (e >= Etot) return;
    int s = srcs[e], d = dsts[e];
    float4 a0 = *(const float4*)(as + (size_t)s * 4);
    float4 b0 = *(const float4*)(ad + (size_t)d * 4);
    float4 a1 = *(const float4*)(as + N4 + (size_t)s * 4);
    float4 b1 = *(const float4*)(ad + N4 + (size_t)d * 4);
    float4 p0, p1;
    p0.x = __expf(LEAKY(a0.x + b0.x));
    p0.y = __expf(LEAKY(a0.y + b0.y));
    p0.z = __expf(LEAKY(a0.z + b0.z));
    p0.w = __expf(LEAKY(a0.w + b0.w));
    p1.x = __expf(LEAKY(a1.x + b1.x));
    p1.y = __expf(LEAKY(a1.y + b1.y));
    p1.z = __expf(LEAKY(a1.z + b1.z));
    p1.w = __expf(LEAKY(a1.w + b1.w));
    *(float4*)(pw + (size_t)e * 8)     = p0;
    *(float4*)(pw + (size_t)e * 8 + 4) = p1;
}

// ---------------- layer-1 aggregate: packed 16B gather, shfl-broadcast srcs ----------------

#define ACC8(g, pa, pb) {                                                      \
    den[0] += (pa).x; acc[0] += (pa).x * lo16((g).x);                          \
    den[1] += (pa).y; acc[1] += (pa).y * hi16((g).x);                          \
    den[2] += (pa).z; acc[2] += (pa).z * lo16((g).y);                          \
    den[3] += (pa).w; acc[3] += (pa).w * hi16((g).y);                          \
    den[4] += (pb).x; acc[4] += (pb).x * lo16((g).z);                          \
    den[5] += (pb).y; acc[5] += (pb).y * hi16((g).z);                          \
    den[6] += (pb).z; acc[6] += (pb).z * lo16((g).w);                          \
    den[7] += (pb).w; acc[7] += (pb).w * hi16((g).w); }

__global__ __launch_bounds__(256) void agg1_both(const unsigned short* __restrict__ hp,
                                                 const float* __restrict__ pw,
                                                 const int* __restrict__ off, const int* __restrict__ srcs,
                                                 const float* __restrict__ b1,
                                                 unsigned short* __restrict__ x2, int N) {
    int n = blockIdx.x * 4 + (threadIdx.x >> 6);
    int lane = threadIdx.x & 63;
    if (n >= N) return;
    int r0 = off[n], r1 = off[n + 1];

    float acc[8] = {0.f, 0.f, 0.f, 0.f, 0.f, 0.f, 0.f, 0.f};
    float den[8] = {0.f, 0.f, 0.f, 0.f, 0.f, 0.f, 0.f, 0.f};

    for (int base = r0; base < r1; base += 64) {
        int cnt = min(64, r1 - base);
        int my = (base + lane < r1) ? srcs[base + lane] : 0;
        int j = 0;
        for (; j + 2 <= cnt; j += 2) {
            int s0 = __shfl(my, j);
            int s1 = __shfl(my, j + 1);
            uint4 g0 = *(const uint4*)(hp + (size_t)s0 * 512 + lane * 8);
            uint4 g1 = *(const uint4*)(hp + (size_t)s1 * 512 + lane * 8);
            float4 pa0 = *(const float4*)(pw + (size_t)(base + j) * 8);
            float4 pb0 = *(const float4*)(pw + (size_t)(base + j) * 8 + 4);
            float4 pa1 = *(const float4*)(pw + (size_t)(base + j + 1) * 8);
            float4 pb1 = *(const float4*)(pw + (size_t)(base + j + 1) * 8 + 4);
            ACC8(g0, pa0, pb0);
            ACC8(g1, pa1, pb1);
        }
        if (j < cnt) {
            int s0 = __shfl(my, j);
            uint4 g0 = *(const uint4*)(hp + (size_t)s0 * 512 + lane * 8);
            float4 pa0 = *(const float4*)(pw + (size_t)(base + j) * 8);
            float4 pb0 = *(const float4*)(pw + (size_t)(base + j) * 8 + 4);
            ACC8(g0, pa0, pb0);
        }
    }

    unsigned short* xo = x2 + (size_t)n * 512;
#pragma unroll
    for (int q = 0; q < 8; ++q) {
        int k = q >> 2, hd = q & 3;
        int ofs = k * 256 + hd * 64 + lane;
        float o = acc[q] / (den[q] + 1e-16f) + b1[ofs];
        o = o > 0.f ? o : (__expf(o) - 1.0f);
        xo[ofs] = f2bf(o);
    }
}

// ---------------- GEMM2 MFMA: x2 [N,512] @ wt2 -> h2 [N,16] + fused alpha2 ----------------

__global__ __launch_bounds__(256) void gemm2_mfma(const unsigned short* __restrict__ x2,
                                                  const unsigned short* __restrict__ wt2,
                                                  const float* __restrict__ asw2, const float* __restrict__ adw2,
                                                  float* __restrict__ h2,
                                                  float* __restrict__ as2, float* __restrict__ ad2, int N) {
    int t = threadIdx.x;
    int w = t >> 6, l = t & 63;
    int rowbase = (blockIdx.x * 4 + w) * 16;
    if (rowbase >= N) return;
    int lr = l & 15, lg = l >> 4;

    f32x4 acc = (f32x4){0.f, 0.f, 0.f, 0.f};
    const unsigned short* ap = x2 + (size_t)(rowbase + lr) * 512 + lg * 8;
#pragma unroll
    for (int s = 0; s < 16; ++s) {
        bf16x8 av = *(const bf16x8*)(ap + s * 32);
        bf16x8 bv = *(const bf16x8*)(wt2 + ((size_t)s * 64 + l) * 8);
        acc = __builtin_amdgcn_mfma_f32_16x16x32_bf16(av, bv, acc, 0, 0, 0);
    }

    float asv = asw2[lr], adv = adw2[lr];
#pragma unroll
    for (int i = 0; i < 4; ++i) {
        int row = rowbase + lg * 4 + i;
        if (row < N) h2[(size_t)row * 16 + lr] = acc[i];
        float sv = acc[i] * asv, dv = acc[i] * adv;
#pragma unroll
        for (int o = 1; o < 16; o <<= 1) {
            sv += __shfl_xor(sv, o);
            dv += __shfl_xor(dv, o);
        }
        if (lr == 0 && row < N) { as2[row] = sv; ad2[row] = dv; }
    }
}

// ---------------- layer-2 aggregate, inline softmax, 16 edges in flight -> out ----------------

__global__ __launch_bounds__(256) void agg2(const float* __restrict__ h2,
                                            const float* __restrict__ as2, const float* __restrict__ ad2,
                                            const int* __restrict__ off, const int* __restrict__ srcs,
                                            const float* __restrict__ bias2, float* __restrict__ out, int N) {
    int n = blockIdx.x * 4 + (threadIdx.x >> 6);
    int lane = threadIdx.x & 63;
    if (n >= N) return;
    int r0 = off[n], r1 = off[n + 1];
    float adn = ad2[n];
    int cg = lane & 3, eo = lane >> 2;   // 16 edges in flight x 4 channel-groups

    float4 acc = make_float4(0.f, 0.f, 0.f, 0.f);
    float den = 0.f;
    for (int base = r0; base + eo < r1; base += 16) {
        int e = base + eo;
        int s = srcs[e];
        float p = __expf(LEAKY(as2[s] + adn));
        float4 hv = *(const float4*)(h2 + (size_t)s * 16 + cg * 4);
        den += p;
        acc.x += p * hv.x; acc.y += p * hv.y;
        acc.z += p * hv.z; acc.w += p * hv.w;
    }
#pragma unroll
    for (int o = 4; o < 64; o <<= 1) {
        acc.x += __shfl_xor(acc.x, o);
        acc.y += __shfl_xor(acc.y, o);
        acc.z += __shfl_xor(acc.z, o);
        acc.w += __shfl_xor(acc.w, o);
        den   += __shfl_xor(den, o);
    }
    if (eo == 0) {
        float inv = 1.f / (den + 1e-16f);
        float4 b = *(const float4*)(bias2 + cg * 4);
        float4 o4;
        o4.x = acc.x * inv + b.x;
        o4.y = acc.y * inv + b.y;
        o4.z = acc.z * inv + b.z;
        o4.w = acc.w * inv + b.w;
        *(float4*)(out + (size_t)n * 16 + cg * 4) = o4;
    }
}

// ---------------- launch ----------------

extern "C" void kernel_launch(void* const* d_in, const int* in_sizes, int n_in,
                              void* d_out, int out_size, void* d_ws, size_t ws_size,
                              hipStream_t stream) {
    const float* x_list = (const float*)d_in[0];   // [2, N, 128]
    const int*   ei     = (const int*)d_in[1];     // [2, E] int32
    const float* W1     = (const float*)d_in[2];   // [2, 128, 256]
    const float* as1w   = (const float*)d_in[3];   // [2, 4, 64]
    const float* ad1w   = (const float*)d_in[4];
    const float* b1     = (const float*)d_in[5];   // [2, 256]
    const float* W2     = (const float*)d_in[6];   // [512, 16]
    const float* as2w   = (const float*)d_in[7];
    const float* ad2w   = (const float*)d_in[8];
    const float* b2     = (const float*)d_in[9];   // [16]
    float* out = (float*)d_out;

    const int N = in_sizes[0] / 256;   // 50000
    const int E = in_sizes[1] / 2;     // 800000
    const int Etot = E + N;
    const int N4 = N * 4;

    char* ws = (char*)d_ws;
    size_t woff = 0;
    auto alloc = [&](size_t bytes) {
        char* p = ws + woff;
        woff = (woff + bytes + 255) & ~(size_t)255;
        return p;
    };
    int*   csr    = (int*)alloc((size_t)(N + 1) * 4);
    int*   cursor = (int*)alloc((size_t)N * 4);
    int*   srcs   = (int*)alloc((size_t)Etot * 4);
    int*   dsts   = (int*)alloc((size_t)Etot * 4);
    int*   bsum   = (int*)alloc(512 * 4);
    int*   boff   = (int*)alloc(512 * 4);
    float* as1    = (float*)alloc((size_t)N4 * 2 * 4);   // [2][N][4]
    float* ad1    = (float*)alloc((size_t)N4 * 2 * 4);
    float* as2    = (float*)alloc((size_t)N * 4);
    float* ad2    = (float*)alloc((size_t)N * 4);
    unsigned short* wt1 = (unsigned short*)alloc(2 * 32768 * 2);
    unsigned short* wt2 = (unsigned short*)alloc(16 * 64 * 8 * 2);
    unsigned short* hp  = (unsigned short*)alloc((size_t)N * 512 * 2);   // [n][64][2][4] bf16, 51.2 MB
    unsigned short* x2  = (unsigned short*)alloc((size_t)N * 512 * 2);   // bf16, 51.2 MB
    float* h2     = (float*)alloc((size_t)N * 16 * 4);
    float* pw     = (float*)alloc((size_t)Etot * 8 * 4);  // 27.2 MB

    // CSR by dst
    hipMemsetAsync(cursor, 0, (size_t)N * 4, stream);
    int gE = (Etot + 255) / 256;
    count_deg<<<gE, 256, 0, stream>>>(ei, cursor, E, Etot);
    int nb = (N + 511) / 512;
    scan_block<<<nb, 512, 0, stream>>>(cursor, csr, bsum, N);
    scan_sums<<<1, 512, 0, stream>>>(bsum, boff, nb);
    finalize_off<<<(N + 255) / 256, 256, 0, stream>>>(csr, cursor, boff, N, Etot);
    scatter_edge<<<gE, 256, 0, stream>>>(ei, cursor, srcs, dsts, E, Etot);

    wpack1<<<32, 256, 0, stream>>>(W1, wt1);
    wpack2<<<4, 256, 0, stream>>>(W2, wt2);

    // layer 1
    gemm1_mfma<<<dim3((N + 63) / 64, 2), 256, 0, stream>>>(x_list, wt1, as1w, ad1w, hp, as1, ad1, N);
    edge_w1<<<gE, 256, 0, stream>>>(srcs, dsts, as1, ad1, pw, Etot, N4);
    agg1_both<<<(N + 3) / 4, 256, 0, stream>>>(hp, pw, csr, srcs, b1, x2, N);

    // layer 2
    gemm2_mfma<<<(N + 63) / 64, 256, 0, stream>>>(x2, wt2, as2w, ad2w, h2, as2, ad2, N);
    agg2<<<(N + 3) / 4, 256, 0, stream>>>(h2, as2, ad2, csr, srcs, b2, out, N);
}

// Round 9
// 311.923 us; speedup vs baseline: 2.1609x; 1.0529x over previous
//
#include <hip/hip_runtime.h>

#define LEAKY(v) ((v) >= 0.0f ? (v) : 0.2f * (v))

typedef __attribute__((ext_vector_type(8))) short bf16x8;
typedef __attribute__((ext_vector_type(4))) float f32x4;

__device__ __forceinline__ unsigned short f2bf(float f) {
    unsigned int u = __float_as_uint(f);
    unsigned int r = u + 0x7FFFu + ((u >> 16) & 1u);
    return (unsigned short)(r >> 16);
}
__device__ __forceinline__ unsigned int pk2(float a, float b) {
    return (unsigned int)f2bf(a) | ((unsigned int)f2bf(b) << 16);
}
__device__ __forceinline__ float lo16(unsigned int u) { return __uint_as_float(u << 16); }
__device__ __forceinline__ float hi16(unsigned int u) { return __uint_as_float(u & 0xFFFF0000u); }

// ---------------- CSR build ----------------

__global__ __launch_bounds__(256) void count_deg(const int* ei, int* deg, int E, int Etot) {
    int i = blockIdx.x * 256 + threadIdx.x;
    if (i >= Etot) return;
    int d = (i < E) ? ei[E + i] : (i - E);
    atomicAdd(&deg[d], 1);
}

__global__ __launch_bounds__(512) void scan_block(const int* deg, int* excl, int* bsum, int n) {
    __shared__ int s[512];
    int t = threadIdx.x;
    int i = blockIdx.x * 512 + t;
    int v = (i < n) ? deg[i] : 0;
    s[t] = v;
    __syncthreads();
    for (int d = 1; d < 512; d <<= 1) {
        int x = 0;
        if (t >= d) x = s[t - d];
        __syncthreads();
        if (t >= d) s[t] += x;
        __syncthreads();
    }
    if (i < n) excl[i] = s[t] - v;
    if (t == 511) bsum[blockIdx.x] = s[511];
}

__global__ __launch_bounds__(512) void scan_sums(const int* bsum, int* boff, int nb) {
    __shared__ int s[512];
    int t = threadIdx.x;
    int v = (t < nb) ? bsum[t] : 0;
    s[t] = v;
    __syncthreads();
    for (int d = 1; d < 512; d <<= 1) {
        int x = 0;
        if (t >= d) x = s[t - d];
        __syncthreads();
        if (t >= d) s[t] += x;
        __syncthreads();
    }
    boff[t] = s[t] - v;
}

__global__ __launch_bounds__(256) void finalize_off(int* csr, int* cursor, const int* boff, int n, int etot) {
    int i = blockIdx.x * 256 + threadIdx.x;
    if (i < n) {
        int v = csr[i] + boff[i >> 9];
        csr[i] = v;
        cursor[i] = v;
    }
    if (i == 0) csr[n] = etot;
}

__global__ __launch_bounds__(256) void scatter_src(const int* ei, int* cursor, int* srcs, int E, int Etot) {
    int i = blockIdx.x * 256 + threadIdx.x;
    if (i >= Etot) return;
    int s, d;
    if (i < E) { s = ei[i]; d = ei[E + i]; }
    else       { s = i - E; d = s; }
    int pos = atomicAdd(&cursor[d], 1);
    srcs[pos] = s;
}

// ---------------- weight packing ----------------

// W1 (f32 [2][128][256]) -> wt1 (bf16 [2][256 c][128 k], transposed, swizzle baked)
__global__ __launch_bounds__(256) void wpack1(const float* __restrict__ W1, unsigned short* __restrict__ wt1) {
    int id = blockIdx.x * 256 + threadIdx.x;      // conv*4096 + c*16 + q
    if (id >= 8192) return;
    int conv = id >> 12, rem = id & 4095;
    int c = rem >> 4, q = rem & 15;
    const float* src = W1 + (size_t)conv * 32768 + (size_t)(q * 8) * 256 + c;
    float w[8];
#pragma unroll
    for (int j = 0; j < 8; ++j) w[j] = src[j * 256];
    uint4 v;
    v.x = pk2(w[0], w[1]); v.y = pk2(w[2], w[3]);
    v.z = pk2(w[4], w[5]); v.w = pk2(w[6], w[7]);
    *(uint4*)(wt1 + (size_t)conv * 32768 + c * 128 + ((q ^ (c & 7)) << 3)) = v;
}

// W2 (f32 [512][16]) -> wt2 (bf16 B-fragment image [16 steps][64 lanes][8])
__global__ __launch_bounds__(256) void wpack2(const float* __restrict__ W2, unsigned short* __restrict__ wt2) {
    int id = blockIdx.x * 256 + threadIdx.x;      // s*64 + l
    if (id >= 1024) return;
    int s = id >> 6, l = id & 63;
    const float* src = W2 + (size_t)(s * 32 + (l >> 4) * 8) * 16 + (l & 15);
    float w[8];
#pragma unroll
    for (int j = 0; j < 8; ++j) w[j] = src[j * 16];
    uint4 v;
    v.x = pk2(w[0], w[1]); v.y = pk2(w[2], w[3]);
    v.z = pk2(w[4], w[5]); v.w = pk2(w[6], w[7]);
    *(uint4*)(wt2 + (size_t)id * 8) = v;
}

// ---------------- GEMM1 MFMA (fused f32->bf16 staging + fused alpha) ----------------
// block: 64 rows x 256 cols; 4 waves, wave w = head w
// SWAPPED mfma operands -> C^T register layout: thread holds 4 consecutive c per (mt,nt)
// hp layout: [n][conv(2)][head(4)][c(64)] bf16  (1 KB per node)
// aad layout: [n][16] f32: [0..7]=as (conv*4+head), [8..15]=ad

__global__ __launch_bounds__(256) void gemm1_mfma(const float* __restrict__ x_list,
                                                  const unsigned short* __restrict__ wt1,
                                                  const float* __restrict__ asw, const float* __restrict__ adw,
                                                  unsigned short* __restrict__ hp,
                                                  float* __restrict__ aad, int N) {
    __shared__ unsigned short As[64 * 128];    // 16 KB swizzled
    __shared__ unsigned short Ws[256 * 128];   // 64 KB swizzled
    int conv = blockIdx.y;
    int t = threadIdx.x;
    int w = t >> 6, l = t & 63;

    const float* xg = x_list + (size_t)conv * N * 128;
#pragma unroll
    for (int p = 0; p < 4; ++p) {
        int id = p * 256 + t;
        int row = id >> 4, q = id & 15;
        int grow = blockIdx.x * 64 + row;
        uint4 v = make_uint4(0, 0, 0, 0);
        if (grow < N) {
            const float* src = xg + (size_t)grow * 128 + q * 8;
            float4 a = *(const float4*)src;
            float4 b = *(const float4*)(src + 4);
            v.x = pk2(a.x, a.y); v.y = pk2(a.z, a.w);
            v.z = pk2(b.x, b.y); v.w = pk2(b.z, b.w);
        }
        *(uint4*)(As + row * 128 + ((q ^ (row & 7)) << 3)) = v;
    }
    const uint4* wsrc = (const uint4*)(wt1 + (size_t)conv * 32768);
#pragma unroll
    for (int p = 0; p < 16; ++p) {
        int id = p * 256 + t;
        *(uint4*)(Ws + (size_t)id * 8) = wsrc[id];
    }
    __syncthreads();

    f32x4 acc[4][4];
#pragma unroll
    for (int mt = 0; mt < 4; ++mt)
#pragma unroll
        for (int nt = 0; nt < 4; ++nt) acc[mt][nt] = (f32x4){0.f, 0.f, 0.f, 0.f};

    int lr = l & 15, lg = l >> 4;
#pragma unroll
    for (int s = 0; s < 4; ++s) {
        int kq = s * 4 + lg;
        bf16x8 af[4], bf[4];
#pragma unroll
        for (int mt = 0; mt < 4; ++mt) {
            int r = mt * 16 + lr;
            af[mt] = *(const bf16x8*)(As + r * 128 + ((kq ^ (r & 7)) << 3));
        }
#pragma unroll
        for (int nt = 0; nt < 4; ++nt) {
            int c = w * 64 + nt * 16 + lr;
            bf[nt] = *(const bf16x8*)(Ws + c * 128 + ((kq ^ (c & 7)) << 3));
        }
        // swapped operands: D = (Wcols x K) . (K x Xrows) = C^T
#pragma unroll
        for (int mt = 0; mt < 4; ++mt)
#pragma unroll
            for (int nt = 0; nt < 4; ++nt)
                acc[mt][nt] = __builtin_amdgcn_mfma_f32_16x16x32_bf16(bf[nt], af[mt], acc[mt][nt], 0, 0, 0);
    }

    // epilogue: acc[mt][nt][i]: row = bm*64+mt*16+lr, c = nt*16+lg*4+i (consecutive i!)
    float4 aswv[4], adwv[4];
#pragma unroll
    for (int nt = 0; nt < 4; ++nt) {
        aswv[nt] = *(const float4*)(asw + conv * 256 + w * 64 + nt * 16 + lg * 4);
        adwv[nt] = *(const float4*)(adw + conv * 256 + w * 64 + nt * 16 + lg * 4);
    }
#pragma unroll
    for (int mt = 0; mt < 4; ++mt) {
        int grow = blockIdx.x * 64 + mt * 16 + lr;
        bool ok = grow < N;
        float sv = 0.f, dv = 0.f;
#pragma unroll
        for (int nt = 0; nt < 4; ++nt) {
            f32x4 a = acc[mt][nt];
            if (ok) {
                uint2 pk;
                pk.x = pk2(a[0], a[1]);
                pk.y = pk2(a[2], a[3]);
                *(uint2*)(hp + (size_t)grow * 512 + conv * 256 + w * 64 + nt * 16 + lg * 4) = pk;
            }
            sv += a[0] * aswv[nt].x + a[1] * aswv[nt].y + a[2] * aswv[nt].z + a[3] * aswv[nt].w;
            dv += a[0] * adwv[nt].x + a[1] * adwv[nt].y + a[2] * adwv[nt].z + a[3] * adwv[nt].w;
        }
        sv += __shfl_xor(sv, 16); sv += __shfl_xor(sv, 32);
        dv += __shfl_xor(dv, 16); dv += __shfl_xor(dv, 32);
        if (l < 16 && ok) {
            aad[(size_t)grow * 16 + conv * 4 + w]     = sv;
            aad[(size_t)grow * 16 + 8 + conv * 4 + w] = dv;
        }
    }
}

// ---------------- layer-1 aggregate: inline softmax, per-lane (conv,head,c8) ----------------
// wave per node; lane = ch*8 + c8/8 where ch = conv*4+head; lane reads hp row bytes [lane*16, +16)

__global__ __launch_bounds__(256) void agg1_both(const unsigned short* __restrict__ hp,
                                                 const float* __restrict__ aad,
                                                 const int* __restrict__ off, const int* __restrict__ srcs,
                                                 const float* __restrict__ b1,
                                                 unsigned short* __restrict__ x2, int N) {
    int n = blockIdx.x * 4 + (threadIdx.x >> 6);
    int lane = threadIdx.x & 63;
    if (n >= N) return;
    int r0 = off[n], r1 = off[n + 1];
    int ch = lane >> 3;   // conv*4 + head
    float ad_l = aad[(size_t)n * 16 + 8 + ch];

    float acc[8] = {0.f, 0.f, 0.f, 0.f, 0.f, 0.f, 0.f, 0.f};
    float den = 0.f;

    for (int base = r0; base < r1; base += 64) {
        int cnt = min(64, r1 - base);
        int my = (base + lane < r1) ? srcs[base + lane] : 0;
        int j = 0;
        for (; j + 2 <= cnt; j += 2) {
            int s0 = __shfl(my, j);
            int s1 = __shfl(my, j + 1);
            uint4 g0 = *(const uint4*)(hp + (size_t)s0 * 512 + lane * 8);
            uint4 g1 = *(const uint4*)(hp + (size_t)s1 * 512 + lane * 8);
            float a0 = aad[(size_t)s0 * 16 + ch];
            float a1 = aad[(size_t)s1 * 16 + ch];
            float p0 = __expf(LEAKY(a0 + ad_l));
            float p1 = __expf(LEAKY(a1 + ad_l));
            den += p0; den += p1;
            acc[0] += p0 * lo16(g0.x); acc[1] += p0 * hi16(g0.x);
            acc[2] += p0 * lo16(g0.y); acc[3] += p0 * hi16(g0.y);
            acc[4] += p0 * lo16(g0.z); acc[5] += p0 * hi16(g0.z);
            acc[6] += p0 * lo16(g0.w); acc[7] += p0 * hi16(g0.w);
            acc[0] += p1 * lo16(g1.x); acc[1] += p1 * hi16(g1.x);
            acc[2] += p1 * lo16(g1.y); acc[3] += p1 * hi16(g1.y);
            acc[4] += p1 * lo16(g1.z); acc[5] += p1 * hi16(g1.z);
            acc[6] += p1 * lo16(g1.w); acc[7] += p1 * hi16(g1.w);
        }
        if (j < cnt) {
            int s0 = __shfl(my, j);
            uint4 g0 = *(const uint4*)(hp + (size_t)s0 * 512 + lane * 8);
            float a0 = aad[(size_t)s0 * 16 + ch];
            float p0 = __expf(LEAKY(a0 + ad_l));
            den += p0;
            acc[0] += p0 * lo16(g0.x); acc[1] += p0 * hi16(g0.x);
            acc[2] += p0 * lo16(g0.y); acc[3] += p0 * hi16(g0.y);
            acc[4] += p0 * lo16(g0.z); acc[5] += p0 * hi16(g0.z);
            acc[6] += p0 * lo16(g0.w); acc[7] += p0 * hi16(g0.w);
        }
    }

    float inv = 1.f / (den + 1e-16f);
    const float* bp = b1 + lane * 8;
    unsigned int ow[4];
#pragma unroll
    for (int q = 0; q < 4; ++q) {
        float o0 = acc[q * 2 + 0] * inv + bp[q * 2 + 0];
        float o1 = acc[q * 2 + 1] * inv + bp[q * 2 + 1];
        o0 = o0 > 0.f ? o0 : (__expf(o0) - 1.0f);
        o1 = o1 > 0.f ? o1 : (__expf(o1) - 1.0f);
        ow[q] = pk2(o0, o1);
    }
    uint4 ov = make_uint4(ow[0], ow[1], ow[2], ow[3]);
    *(uint4*)(x2 + (size_t)n * 512 + lane * 8) = ov;
}

// ---------------- GEMM2 MFMA: x2 [N,512] @ wt2 -> h2 [N,16] + fused alpha2 ----------------

__global__ __launch_bounds__(256) void gemm2_mfma(const unsigned short* __restrict__ x2,
                                                  const unsigned short* __restrict__ wt2,
                                                  const float* __restrict__ asw2, const float* __restrict__ adw2,
                                                  float* __restrict__ h2,
                                                  float* __restrict__ as2, float* __restrict__ ad2, int N) {
    int t = threadIdx.x;
    int w = t >> 6, l = t & 63;
    int rowbase = (blockIdx.x * 4 + w) * 16;
    if (rowbase >= N) return;
    int lr = l & 15, lg = l >> 4;

    f32x4 acc = (f32x4){0.f, 0.f, 0.f, 0.f};
    const unsigned short* ap = x2 + (size_t)(rowbase + lr) * 512 + lg * 8;
#pragma unroll
    for (int s = 0; s < 16; ++s) {
        bf16x8 av = *(const bf16x8*)(ap + s * 32);
        bf16x8 bv = *(const bf16x8*)(wt2 + ((size_t)s * 64 + l) * 8);
        acc = __builtin_amdgcn_mfma_f32_16x16x32_bf16(av, bv, acc, 0, 0, 0);
    }

    float asv = asw2[lr], adv = adw2[lr];
#pragma unroll
    for (int i = 0; i < 4; ++i) {
        int row = rowbase + lg * 4 + i;
        if (row < N) h2[(size_t)row * 16 + lr] = acc[i];
        float sv = acc[i] * asv, dv = acc[i] * adv;
#pragma unroll
        for (int o = 1; o < 16; o <<= 1) {
            sv += __shfl_xor(sv, o);
            dv += __shfl_xor(dv, o);
        }
        if (lr == 0 && row < N) { as2[row] = sv; ad2[row] = dv; }
    }
}

// ---------------- layer-2 aggregate, inline softmax, 16 edges in flight -> out ----------------

__global__ __launch_bounds__(256) void agg2(const float* __restrict__ h2,
                                            const float* __restrict__ as2, const float* __restrict__ ad2,
                                            const int* __restrict__ off, const int* __restrict__ srcs,
                                            const float* __restrict__ bias2, float* __restrict__ out, int N) {
    int n = blockIdx.x * 4 + (threadIdx.x >> 6);
    int lane = threadIdx.x & 63;
    if (n >= N) return;
    int r0 = off[n], r1 = off[n + 1];
    float adn = ad2[n];
    int cg = lane & 3, eo = lane >> 2;   // 16 edges in flight x 4 channel-groups

    float4 acc = make_float4(0.f, 0.f, 0.f, 0.f);
    float den = 0.f;
    for (int base = r0; base + eo < r1; base += 16) {
        int e = base + eo;
        int s = srcs[e];
        float p = __expf(LEAKY(as2[s] + adn));
        float4 hv = *(const float4*)(h2 + (size_t)s * 16 + cg * 4);
        den += p;
        acc.x += p * hv.x; acc.y += p * hv.y;
        acc.z += p * hv.z; acc.w += p * hv.w;
    }
#pragma unroll
    for (int o = 4; o < 64; o <<= 1) {
        acc.x += __shfl_xor(acc.x, o);
        acc.y += __shfl_xor(acc.y, o);
        acc.z += __shfl_xor(acc.z, o);
        acc.w += __shfl_xor(acc.w, o);
        den   += __shfl_xor(den, o);
    }
    if (eo == 0) {
        float inv = 1.f / (den + 1e-16f);
        float4 b = *(const float4*)(bias2 + cg * 4);
        float4 o4;
        o4.x = acc.x * inv + b.x;
        o4.y = acc.y * inv + b.y;
        o4.z = acc.z * inv + b.z;
        o4.w = acc.w * inv + b.w;
        *(float4*)(out + (size_t)n * 16 + cg * 4) = o4;
    }
}

// ---------------- launch ----------------

extern "C" void kernel_launch(void* const* d_in, const int* in_sizes, int n_in,
                              void* d_out, int out_size, void* d_ws, size_t ws_size,
                              hipStream_t stream) {
    const float* x_list = (const float*)d_in[0];   // [2, N, 128]
    const int*   ei     = (const int*)d_in[1];     // [2, E] int32
    const float* W1     = (const float*)d_in[2];   // [2, 128, 256]
    const float* as1w   = (const float*)d_in[3];   // [2, 4, 64]
    const float* ad1w   = (const float*)d_in[4];
    const float* b1     = (const float*)d_in[5];   // [2, 256]
    const float* W2     = (const float*)d_in[6];   // [512, 16]
    const float* as2w   = (const float*)d_in[7];
    const float* ad2w   = (const float*)d_in[8];
    const float* b2     = (const float*)d_in[9];   // [16]
    float* out = (float*)d_out;

    const int N = in_sizes[0] / 256;   // 50000
    const int E = in_sizes[1] / 2;     // 800000
    const int Etot = E + N;

    char* ws = (char*)d_ws;
    size_t woff = 0;
    auto alloc = [&](size_t bytes) {
        char* p = ws + woff;
        woff = (woff + bytes + 255) & ~(size_t)255;
        return p;
    };
    int*   csr    = (int*)alloc((size_t)(N + 1) * 4);
    int*   cursor = (int*)alloc((size_t)N * 4);
    int*   srcs   = (int*)alloc((size_t)Etot * 4);
    int*   bsum   = (int*)alloc(512 * 4);
    int*   boff   = (int*)alloc(512 * 4);
    float* aad    = (float*)alloc((size_t)N * 16 * 4);   // [n][as(8) | ad(8)], 3.2 MB
    float* as2    = (float*)alloc((size_t)N * 4);
    float* ad2    = (float*)alloc((size_t)N * 4);
    unsigned short* wt1 = (unsigned short*)alloc(2 * 32768 * 2);
    unsigned short* wt2 = (unsigned short*)alloc(16 * 64 * 8 * 2);
    unsigned short* hp  = (unsigned short*)alloc((size_t)N * 512 * 2);   // [n][conv][head][c] bf16, 51.2 MB
    unsigned short* x2  = (unsigned short*)alloc((size_t)N * 512 * 2);   // bf16, 51.2 MB
    float* h2     = (float*)alloc((size_t)N * 16 * 4);

    // CSR by dst
    hipMemsetAsync(cursor, 0, (size_t)N * 4, stream);
    int gE = (Etot + 255) / 256;
    count_deg<<<gE, 256, 0, stream>>>(ei, cursor, E, Etot);
    int nb = (N + 511) / 512;
    scan_block<<<nb, 512, 0, stream>>>(cursor, csr, bsum, N);
    scan_sums<<<1, 512, 0, stream>>>(bsum, boff, nb);
    finalize_off<<<(N + 255) / 256, 256, 0, stream>>>(csr, cursor, boff, N, Etot);
    scatter_src<<<gE, 256, 0, stream>>>(ei, cursor, srcs, E, Etot);

    wpack1<<<32, 256, 0, stream>>>(W1, wt1);
    wpack2<<<4, 256, 0, stream>>>(W2, wt2);

    // layer 1
    gemm1_mfma<<<dim3((N + 63) / 64, 2), 256, 0, stream>>>(x_list, wt1, as1w, ad1w, hp, aad, N);
    agg1_both<<<(N + 3) / 4, 256, 0, stream>>>(hp, aad, csr, srcs, b1, x2, N);

    // layer 2
    gemm2_mfma<<<(N + 63) / 64, 256, 0, stream>>>(x2, wt2, as2w, ad2w, h2, as2, ad2, N);
    agg2<<<(N + 3) / 4, 256, 0, stream>>>(h2, as2, ad2, csr, srcs, b2, out, N);
}

// Round 10
// 308.470 us; speedup vs baseline: 2.1850x; 1.0112x over previous
//
#include <hip/hip_runtime.h>

#define LEAKY(v) ((v) >= 0.0f ? (v) : 0.2f * (v))

typedef __attribute__((ext_vector_type(8))) short bf16x8;
typedef __attribute__((ext_vector_type(4))) float f32x4;

__device__ __forceinline__ unsigned short f2bf(float f) {
    unsigned int u = __float_as_uint(f);
    unsigned int r = u + 0x7FFFu + ((u >> 16) & 1u);
    return (unsigned short)(r >> 16);
}
__device__ __forceinline__ unsigned int pk2(float a, float b) {
    return (unsigned int)f2bf(a) | ((unsigned int)f2bf(b) << 16);
}
__device__ __forceinline__ float lo16(unsigned int u) { return __uint_as_float(u << 16); }
__device__ __forceinline__ float hi16(unsigned int u) { return __uint_as_float(u & 0xFFFF0000u); }

// ---------------- CSR build ----------------

__global__ __launch_bounds__(256) void count_deg(const int* ei, int* deg, int E, int Etot) {
    int i = blockIdx.x * 256 + threadIdx.x;
    if (i >= Etot) return;
    int d = (i < E) ? ei[E + i] : (i - E);
    atomicAdd(&deg[d], 1);
}

__global__ __launch_bounds__(512) void scan_block(const int* deg, int* excl, int* bsum, int n) {
    __shared__ int s[512];
    int t = threadIdx.x;
    int i = blockIdx.x * 512 + t;
    int v = (i < n) ? deg[i] : 0;
    s[t] = v;
    __syncthreads();
    for (int d = 1; d < 512; d <<= 1) {
        int x = 0;
        if (t >= d) x = s[t - d];
        __syncthreads();
        if (t >= d) s[t] += x;
        __syncthreads();
    }
    if (i < n) excl[i] = s[t] - v;
    if (t == 511) bsum[blockIdx.x] = s[511];
}

__global__ __launch_bounds__(512) void scan_sums(const int* bsum, int* boff, int nb) {
    __shared__ int s[512];
    int t = threadIdx.x;
    int v = (t < nb) ? bsum[t] : 0;
    s[t] = v;
    __syncthreads();
    for (int d = 1; d < 512; d <<= 1) {
        int x = 0;
        if (t >= d) x = s[t - d];
        __syncthreads();
        if (t >= d) s[t] += x;
        __syncthreads();
    }
    boff[t] = s[t] - v;
}

__global__ __launch_bounds__(256) void finalize_off(int* csr, int* cursor, const int* boff, int n, int etot) {
    int i = blockIdx.x * 256 + threadIdx.x;
    if (i < n) {
        int v = csr[i] + boff[i >> 9];
        csr[i] = v;
        cursor[i] = v;
    }
    if (i == 0) csr[n] = etot;
}

__global__ __launch_bounds__(256) void scatter_edge(const int* ei, int* cursor, int* srcs, int* dsts,
                                                    int E, int Etot) {
    int i = blockIdx.x * 256 + threadIdx.x;
    if (i >= Etot) return;
    int s, d;
    if (i < E) { s = ei[i]; d = ei[E + i]; }
    else       { s = i - E; d = s; }
    int pos = atomicAdd(&cursor[d], 1);
    srcs[pos] = s;
    dsts[pos] = d;
}

// ---------------- weight packing (merged) ----------------
// id < 8192: W1 (f32 [2][128][256]) -> wt1 (bf16 [2][256 c][128 k], transposed, swizzled)
// id in [8192, 9216): W2 (f32 [512][16]) -> wt2 (bf16 B-frag image [16][64][8])

__global__ __launch_bounds__(256) void wpack(const float* __restrict__ W1, unsigned short* __restrict__ wt1,
                                             const float* __restrict__ W2, unsigned short* __restrict__ wt2) {
    int id = blockIdx.x * 256 + threadIdx.x;
    if (id < 8192) {
        int conv = id >> 12, rem = id & 4095;
        int c = rem >> 4, q = rem & 15;
        const float* src = W1 + (size_t)conv * 32768 + (size_t)(q * 8) * 256 + c;
        float w[8];
#pragma unroll
        for (int j = 0; j < 8; ++j) w[j] = src[j * 256];
        uint4 v;
        v.x = pk2(w[0], w[1]); v.y = pk2(w[2], w[3]);
        v.z = pk2(w[4], w[5]); v.w = pk2(w[6], w[7]);
        *(uint4*)(wt1 + (size_t)conv * 32768 + c * 128 + ((q ^ (c & 7)) << 3)) = v;
    } else if (id < 9216) {
        int id2 = id - 8192;
        int s = id2 >> 6, l = id2 & 63;
        const float* src = W2 + (size_t)(s * 32 + (l >> 4) * 8) * 16 + (l & 15);
        float w[8];
#pragma unroll
        for (int j = 0; j < 8; ++j) w[j] = src[j * 16];
        uint4 v;
        v.x = pk2(w[0], w[1]); v.y = pk2(w[2], w[3]);
        v.z = pk2(w[4], w[5]); v.w = pk2(w[6], w[7]);
        *(uint4*)(wt2 + (size_t)id2 * 8) = v;
    }
}

// ---------------- GEMM1 MFMA (fused f32->bf16 staging + fused alpha) ----------------
// block: 64 rows x 256 cols; 4 waves, wave w = head w
// SWAPPED mfma operands -> C^T register layout: thread holds 4 consecutive c per (mt,nt)
// hp layout: [n][conv(2)][head(4)][c(64)] bf16  (1 KB per node)
// aad layout: [n][16] f32: [0..7]=as (conv*4+head), [8..15]=ad

__global__ __launch_bounds__(256) void gemm1_mfma(const float* __restrict__ x_list,
                                                  const unsigned short* __restrict__ wt1,
                                                  const float* __restrict__ asw, const float* __restrict__ adw,
                                                  unsigned short* __restrict__ hp,
                                                  float* __restrict__ aad, int N) {
    __shared__ unsigned short As[64 * 128];    // 16 KB swizzled
    __shared__ unsigned short Ws[256 * 128];   // 64 KB swizzled
    int conv = blockIdx.y;
    int t = threadIdx.x;
    int w = t >> 6, l = t & 63;

    const float* xg = x_list + (size_t)conv * N * 128;
#pragma unroll
    for (int p = 0; p < 4; ++p) {
        int id = p * 256 + t;
        int row = id >> 4, q = id & 15;
        int grow = blockIdx.x * 64 + row;
        uint4 v = make_uint4(0, 0, 0, 0);
        if (grow < N) {
            const float* src = xg + (size_t)grow * 128 + q * 8;
            float4 a = *(const float4*)src;
            float4 b = *(const float4*)(src + 4);
            v.x = pk2(a.x, a.y); v.y = pk2(a.z, a.w);
            v.z = pk2(b.x, b.y); v.w = pk2(b.z, b.w);
        }
        *(uint4*)(As + row * 128 + ((q ^ (row & 7)) << 3)) = v;
    }
    const uint4* wsrc = (const uint4*)(wt1 + (size_t)conv * 32768);
#pragma unroll
    for (int p = 0; p < 16; ++p) {
        int id = p * 256 + t;
        *(uint4*)(Ws + (size_t)id * 8) = wsrc[id];
    }
    __syncthreads();

    f32x4 acc[4][4];
#pragma unroll
    for (int mt = 0; mt < 4; ++mt)
#pragma unroll
        for (int nt = 0; nt < 4; ++nt) acc[mt][nt] = (f32x4){0.f, 0.f, 0.f, 0.f};

    int lr = l & 15, lg = l >> 4;
#pragma unroll
    for (int s = 0; s < 4; ++s) {
        int kq = s * 4 + lg;
        bf16x8 af[4], bf[4];
#pragma unroll
        for (int mt = 0; mt < 4; ++mt) {
            int r = mt * 16 + lr;
            af[mt] = *(const bf16x8*)(As + r * 128 + ((kq ^ (r & 7)) << 3));
        }
#pragma unroll
        for (int nt = 0; nt < 4; ++nt) {
            int c = w * 64 + nt * 16 + lr;
            bf[nt] = *(const bf16x8*)(Ws + c * 128 + ((kq ^ (c & 7)) << 3));
        }
        // swapped operands: D = (Wcols x K) . (K x Xrows) = C^T
#pragma unroll
        for (int mt = 0; mt < 4; ++mt)
#pragma unroll
            for (int nt = 0; nt < 4; ++nt)
                acc[mt][nt] = __builtin_amdgcn_mfma_f32_16x16x32_bf16(bf[nt], af[mt], acc[mt][nt], 0, 0, 0);
    }

    // epilogue: acc[mt][nt][i]: row = bm*64+mt*16+lr, c = nt*16+lg*4+i (consecutive i!)
    float4 aswv[4], adwv[4];
#pragma unroll
    for (int nt = 0; nt < 4; ++nt) {
        aswv[nt] = *(const float4*)(asw + conv * 256 + w * 64 + nt * 16 + lg * 4);
        adwv[nt] = *(const float4*)(adw + conv * 256 + w * 64 + nt * 16 + lg * 4);
    }
#pragma unroll
    for (int mt = 0; mt < 4; ++mt) {
        int grow = blockIdx.x * 64 + mt * 16 + lr;
        bool ok = grow < N;
        float sv = 0.f, dv = 0.f;
#pragma unroll
        for (int nt = 0; nt < 4; ++nt) {
            f32x4 a = acc[mt][nt];
            if (ok) {
                uint2 pk;
                pk.x = pk2(a[0], a[1]);
                pk.y = pk2(a[2], a[3]);
                *(uint2*)(hp + (size_t)grow * 512 + conv * 256 + w * 64 + nt * 16 + lg * 4) = pk;
            }
            sv += a[0] * aswv[nt].x + a[1] * aswv[nt].y + a[2] * aswv[nt].z + a[3] * aswv[nt].w;
            dv += a[0] * adwv[nt].x + a[1] * adwv[nt].y + a[2] * adwv[nt].z + a[3] * adwv[nt].w;
        }
        sv += __shfl_xor(sv, 16); sv += __shfl_xor(sv, 32);
        dv += __shfl_xor(dv, 16); dv += __shfl_xor(dv, 32);
        if (l < 16 && ok) {
            aad[(size_t)grow * 16 + conv * 4 + w]     = sv;
            aad[(size_t)grow * 16 + 8 + conv * 4 + w] = dv;
        }
    }
}

// ---------------- edge-parallel softmax weights from aad: pw[e][ch(8)] ----------------

__global__ __launch_bounds__(256) void edge_w1(const int* __restrict__ srcs, const int* __restrict__ dsts,
                                               const float* __restrict__ aad,
                                               float* __restrict__ pw, int Etot) {
    int e = blockIdx.x * 256 + threadIdx.x;
    if (e >= Etot) return;
    int s = srcs[e], d = dsts[e];
    float4 as_lo = *(const float4*)(aad + (size_t)s * 16);
    float4 as_hi = *(const float4*)(aad + (size_t)s * 16 + 4);
    float4 ad_lo = *(const float4*)(aad + (size_t)d * 16 + 8);
    float4 ad_hi = *(const float4*)(aad + (size_t)d * 16 + 12);
    float4 p0, p1;
    p0.x = __expf(LEAKY(as_lo.x + ad_lo.x));
    p0.y = __expf(LEAKY(as_lo.y + ad_lo.y));
    p0.z = __expf(LEAKY(as_lo.z + ad_lo.z));
    p0.w = __expf(LEAKY(as_lo.w + ad_lo.w));
    p1.x = __expf(LEAKY(as_hi.x + ad_hi.x));
    p1.y = __expf(LEAKY(as_hi.y + ad_hi.y));
    p1.z = __expf(LEAKY(as_hi.z + ad_hi.z));
    p1.w = __expf(LEAKY(as_hi.w + ad_hi.w));
    *(float4*)(pw + (size_t)e * 8)     = p0;
    *(float4*)(pw + (size_t)e * 8 + 4) = p1;
}

// ---------------- layer-1 aggregate: per-lane (ch, c8), sequential pw, 16B gathers ----------------
// wave per node; lane = ch*8 + c8 (ch = conv*4+head); lane reads hp row bytes [lane*16, +16)

__global__ __launch_bounds__(256) void agg1_both(const unsigned short* __restrict__ hp,
                                                 const float* __restrict__ pw,
                                                 const int* __restrict__ off, const int* __restrict__ srcs,
                                                 const float* __restrict__ b1,
                                                 unsigned short* __restrict__ x2, int N) {
    int n = blockIdx.x * 4 + (threadIdx.x >> 6);
    int lane = threadIdx.x & 63;
    if (n >= N) return;
    int r0 = off[n], r1 = off[n + 1];
    int ch = lane >> 3;   // conv*4 + head

    float acc[8] = {0.f, 0.f, 0.f, 0.f, 0.f, 0.f, 0.f, 0.f};
    float den = 0.f;

    for (int base = r0; base < r1; base += 64) {
        int cnt = min(64, r1 - base);
        int my = (base + lane < r1) ? srcs[base + lane] : 0;
        int j = 0;
        for (; j + 2 <= cnt; j += 2) {
            int s0 = __shfl(my, j);
            int s1 = __shfl(my, j + 1);
            uint4 g0 = *(const uint4*)(hp + (size_t)s0 * 512 + lane * 8);
            uint4 g1 = *(const uint4*)(hp + (size_t)s1 * 512 + lane * 8);
            float p0 = pw[(size_t)(base + j) * 8 + ch];
            float p1 = pw[(size_t)(base + j + 1) * 8 + ch];
            den += p0; den += p1;
            acc[0] += p0 * lo16(g0.x); acc[1] += p0 * hi16(g0.x);
            acc[2] += p0 * lo16(g0.y); acc[3] += p0 * hi16(g0.y);
            acc[4] += p0 * lo16(g0.z); acc[5] += p0 * hi16(g0.z);
            acc[6] += p0 * lo16(g0.w); acc[7] += p0 * hi16(g0.w);
            acc[0] += p1 * lo16(g1.x); acc[1] += p1 * hi16(g1.x);
            acc[2] += p1 * lo16(g1.y); acc[3] += p1 * hi16(g1.y);
            acc[4] += p1 * lo16(g1.z); acc[5] += p1 * hi16(g1.z);
            acc[6] += p1 * lo16(g1.w); acc[7] += p1 * hi16(g1.w);
        }
        if (j < cnt) {
            int s0 = __shfl(my, j);
            uint4 g0 = *(const uint4*)(hp + (size_t)s0 * 512 + lane * 8);
            float p0 = pw[(size_t)(base + j) * 8 + ch];
            den += p0;
            acc[0] += p0 * lo16(g0.x); acc[1] += p0 * hi16(g0.x);
            acc[2] += p0 * lo16(g0.y); acc[3] += p0 * hi16(g0.y);
            acc[4] += p0 * lo16(g0.z); acc[5] += p0 * hi16(g0.z);
            acc[6] += p0 * lo16(g0.w); acc[7] += p0 * hi16(g0.w);
        }
    }

    float inv = 1.f / (den + 1e-16f);
    const float* bp = b1 + lane * 8;
    unsigned int ow[4];
#pragma unroll
    for (int q = 0; q < 4; ++q) {
        float o0 = acc[q * 2 + 0] * inv + bp[q * 2 + 0];
        float o1 = acc[q * 2 + 1] * inv + bp[q * 2 + 1];
        o0 = o0 > 0.f ? o0 : (__expf(o0) - 1.0f);
        o1 = o1 > 0.f ? o1 : (__expf(o1) - 1.0f);
        ow[q] = pk2(o0, o1);
    }
    uint4 ov = make_uint4(ow[0], ow[1], ow[2], ow[3]);
    *(uint4*)(x2 + (size_t)n * 512 + lane * 8) = ov;
}

// ---------------- GEMM2 MFMA: x2 [N,512] @ wt2 -> h2 [N,16] + fused alpha2 ----------------

__global__ __launch_bounds__(256) void gemm2_mfma(const unsigned short* __restrict__ x2,
                                                  const unsigned short* __restrict__ wt2,
                                                  const float* __restrict__ asw2, const float* __restrict__ adw2,
                                                  float* __restrict__ h2,
                                                  float* __restrict__ as2, float* __restrict__ ad2, int N) {
    int t = threadIdx.x;
    int w = t >> 6, l = t & 63;
    int rowbase = (blockIdx.x * 4 + w) * 16;
    if (rowbase >= N) return;
    int lr = l & 15, lg = l >> 4;

    f32x4 acc = (f32x4){0.f, 0.f, 0.f, 0.f};
    const unsigned short* ap = x2 + (size_t)(rowbase + lr) * 512 + lg * 8;
#pragma unroll
    for (int s = 0; s < 16; ++s) {
        bf16x8 av = *(const bf16x8*)(ap + s * 32);
        bf16x8 bv = *(const bf16x8*)(wt2 + ((size_t)s * 64 + l) * 8);
        acc = __builtin_amdgcn_mfma_f32_16x16x32_bf16(av, bv, acc, 0, 0, 0);
    }

    float asv = asw2[lr], adv = adw2[lr];
#pragma unroll
    for (int i = 0; i < 4; ++i) {
        int row = rowbase + lg * 4 + i;
        if (row < N) h2[(size_t)row * 16 + lr] = acc[i];
        float sv = acc[i] * asv, dv = acc[i] * adv;
#pragma unroll
        for (int o = 1; o < 16; o <<= 1) {
            sv += __shfl_xor(sv, o);
            dv += __shfl_xor(dv, o);
        }
        if (lr == 0 && row < N) { as2[row] = sv; ad2[row] = dv; }
    }
}

// ---------------- layer-2 aggregate, inline softmax, 16 edges in flight -> out ----------------

__global__ __launch_bounds__(256) void agg2(const float* __restrict__ h2,
                                            const float* __restrict__ as2, const float* __restrict__ ad2,
                                            const int* __restrict__ off, const int* __restrict__ srcs,
                                            const float* __restrict__ bias2, float* __restrict__ out, int N) {
    int n = blockIdx.x * 4 + (threadIdx.x >> 6);
    int lane = threadIdx.x & 63;
    if (n >= N) return;
    int r0 = off[n], r1 = off[n + 1];
    float adn = ad2[n];
    int cg = lane & 3, eo = lane >> 2;   // 16 edges in flight x 4 channel-groups

    float4 acc = make_float4(0.f, 0.f, 0.f, 0.f);
    float den = 0.f;
    for (int base = r0; base + eo < r1; base += 16) {
        int e = base + eo;
        int s = srcs[e];
        float p = __expf(LEAKY(as2[s] + adn));
        float4 hv = *(const float4*)(h2 + (size_t)s * 16 + cg * 4);
        den += p;
        acc.x += p * hv.x; acc.y += p * hv.y;
        acc.z += p * hv.z; acc.w += p * hv.w;
    }
#pragma unroll
    for (int o = 4; o < 64; o <<= 1) {
        acc.x += __shfl_xor(acc.x, o);
        acc.y += __shfl_xor(acc.y, o);
        acc.z += __shfl_xor(acc.z, o);
        acc.w += __shfl_xor(acc.w, o);
        den   += __shfl_xor(den, o);
    }
    if (eo == 0) {
        float inv = 1.f / (den + 1e-16f);
        float4 b = *(const float4*)(bias2 + cg * 4);
        float4 o4;
        o4.x = acc.x * inv + b.x;
        o4.y = acc.y * inv + b.y;
        o4.z = acc.z * inv + b.z;
        o4.w = acc.w * inv + b.w;
        *(float4*)(out + (size_t)n * 16 + cg * 4) = o4;
    }
}

// ---------------- launch ----------------

extern "C" void kernel_launch(void* const* d_in, const int* in_sizes, int n_in,
                              void* d_out, int out_size, void* d_ws, size_t ws_size,
                              hipStream_t stream) {
    const float* x_list = (const float*)d_in[0];   // [2, N, 128]
    const int*   ei     = (const int*)d_in[1];     // [2, E] int32
    const float* W1     = (const float*)d_in[2];   // [2, 128, 256]
    const float* as1w   = (const float*)d_in[3];   // [2, 4, 64]
    const float* ad1w   = (const float*)d_in[4];
    const float* b1     = (const float*)d_in[5];   // [2, 256]
    const float* W2     = (const float*)d_in[6];   // [512, 16]
    const float* as2w   = (const float*)d_in[7];
    const float* ad2w   = (const float*)d_in[8];
    const float* b2     = (const float*)d_in[9];   // [16]
    float* out = (float*)d_out;

    const int N = in_sizes[0] / 256;   // 50000
    const int E = in_sizes[1] / 2;     // 800000
    const int Etot = E + N;

    char* ws = (char*)d_ws;
    size_t woff = 0;
    auto alloc = [&](size_t bytes) {
        char* p = ws + woff;
        woff = (woff + bytes + 255) & ~(size_t)255;
        return p;
    };
    int*   csr    = (int*)alloc((size_t)(N + 1) * 4);
    int*   cursor = (int*)alloc((size_t)N * 4);
    int*   srcs   = (int*)alloc((size_t)Etot * 4);
    int*   dsts   = (int*)alloc((size_t)Etot * 4);
    int*   bsum   = (int*)alloc(512 * 4);
    int*   boff   = (int*)alloc(512 * 4);
    float* aad    = (float*)alloc((size_t)N * 16 * 4);   // [n][as(8) | ad(8)], 3.2 MB
    float* as2    = (float*)alloc((size_t)N * 4);
    float* ad2    = (float*)alloc((size_t)N * 4);
    unsigned short* wt1 = (unsigned short*)alloc(2 * 32768 * 2);
    unsigned short* wt2 = (unsigned short*)alloc(16 * 64 * 8 * 2);
    unsigned short* hp  = (unsigned short*)alloc((size_t)N * 512 * 2);   // [n][conv][head][c] bf16, 51.2 MB
    unsigned short* x2  = (unsigned short*)alloc((size_t)N * 512 * 2);   // bf16, 51.2 MB
    float* h2     = (float*)alloc((size_t)N * 16 * 4);
    float* pw     = (float*)alloc((size_t)Etot * 8 * 4);  // 27.2 MB

    // CSR by dst
    hipMemsetAsync(cursor, 0, (size_t)N * 4, stream);
    int gE = (Etot + 255) / 256;
    count_deg<<<gE, 256, 0, stream>>>(ei, cursor, E, Etot);
    int nb = (N + 511) / 512;
    scan_block<<<nb, 512, 0, stream>>>(cursor, csr, bsum, N);
    scan_sums<<<1, 512, 0, stream>>>(bsum, boff, nb);
    finalize_off<<<(N + 255) / 256, 256, 0, stream>>>(csr, cursor, boff, N, Etot);
    scatter_edge<<<gE, 256, 0, stream>>>(ei, cursor, srcs, dsts, E, Etot);

    wpack<<<36, 256, 0, stream>>>(W1, wt1, W2, wt2);

    // layer 1
    gemm1_mfma<<<dim3((N + 63) / 64, 2), 256, 0, stream>>>(x_list, wt1, as1w, ad1w, hp, aad, N);
    edge_w1<<<gE, 256, 0, stream>>>(srcs, dsts, aad, pw, Etot);
    agg1_both<<<(N + 3) / 4, 256, 0, stream>>>(hp, pw, csr, srcs, b1, x2, N);

    // layer 2
    gemm2_mfma<<<(N + 63) / 64, 256, 0, stream>>>(x2, wt2, as2w, ad2w, h2, as2, ad2, N);
    agg2<<<(N + 3) / 4, 256, 0, stream>>>(h2, as2, ad2, csr, srcs, b2, out, N);
}